// Round 2
// baseline (1048.265 us; speedup 1.0000x reference)
//
#include <hip/hip_runtime.h>
#include <hip/hip_bf16.h>
#include <math.h>

typedef __bf16 bf16x8 __attribute__((ext_vector_type(8)));
typedef float  f32x4  __attribute__((ext_vector_type(4)));

static constexpr int kV = 4;
static constexpr int kN = 1536;
static constexpr int kD = 256;
static constexpr int kTopK = 32;

// ---- GEMM (B^T form): out[m][n] = sum_k A[m][k]*B[n][k] (+bias[n]) --------
// A, B, bias are f32; converted to bf16 fragments in-register for MFMA.
// mode 0: plain bf16 write. mode 1: blend a*(v+bias)+(1-a)*H -> f32 out.
// mode 2: plain f32 write.
__global__ __launch_bounds__(256) void gemm_bt_kernel(
    const float* __restrict__ A, const float* __restrict__ Bm,
    const float* __restrict__ bias, int M, int Nc, int K,
    int bBatchRows, int bBatchStride, int mode,
    __bf16* __restrict__ outB, float* __restrict__ outF,
    const float* __restrict__ Hres, const float* __restrict__ alphas,
    int rowsPerView)
{
    int wave = blockIdx.x * (blockDim.x >> 6) + (threadIdx.x >> 6);
    int tilesN = Nc >> 4;
    int tm = wave / tilesN;
    int tn = wave - tm * tilesN;
    if ((tm << 4) >= M) return;
    int lane = threadIdx.x & 63;
    int r    = lane & 15;        // A row / B row (=output col)
    int quad = lane >> 4;        // k-chunk selector
    const float* Ap = A + (size_t)((tm << 4) + r) * K + quad * 8;
    const float* Bp = Bm + (size_t)((tn << 4) + r) * K + quad * 8;
    if (bBatchRows > 0) Bp += (size_t)(((tm << 4)) / bBatchRows) * bBatchStride;
    f32x4 acc = {0.f, 0.f, 0.f, 0.f};
    for (int k0 = 0; k0 < K; k0 += 32) {
        f32x4 a0 = *(const f32x4*)(Ap + k0);
        f32x4 a1 = *(const f32x4*)(Ap + k0 + 4);
        f32x4 b0 = *(const f32x4*)(Bp + k0);
        f32x4 b1 = *(const f32x4*)(Bp + k0 + 4);
        bf16x8 a, b;
#pragma unroll
        for (int j = 0; j < 4; ++j) {
            a[j] = (__bf16)a0[j]; a[j + 4] = (__bf16)a1[j];
            b[j] = (__bf16)b0[j]; b[j + 4] = (__bf16)b1[j];
        }
        acc = __builtin_amdgcn_mfma_f32_16x16x32_bf16(a, b, acc, 0, 0, 0);
    }
    int gn = (tn << 4) + r;      // C/D: col = lane&15
    float bv = bias ? bias[gn] : 0.f;
#pragma unroll
    for (int i = 0; i < 4; ++i) {
        int gm = (tm << 4) + quad * 4 + i;   // C/D: row = quad*4+reg
        float v = acc[i] + bv;
        size_t off = (size_t)gm * Nc + gn;
        if (mode == 0) {
            outB[off] = (__bf16)v;
        } else if (mode == 2) {
            outF[off] = v;
        } else {
            float a_ = alphas[gm / rowsPerView];
            float h  = Hres[off];
            outF[off] = a_ * v + (1.f - a_) * h;
        }
    }
}

// ---- tiny 4x4 attention per (n,h); wave = one head, lane = d -------------
__global__ __launch_bounds__(256) void attn_kernel(const __bf16* __restrict__ qkv,
                                                   float* __restrict__ o)
{
    int n = blockIdx.x;
    int h = threadIdx.x >> 6;
    int d = threadIdx.x & 63;
    float q[4], k[4], vv[4];
#pragma unroll
    for (int s = 0; s < 4; ++s) {
        size_t base = (size_t)(s * kN + n) * 768 + h * 64 + d;
        q[s]  = (float)qkv[base];
        k[s]  = (float)qkv[base + 256];
        vv[s] = (float)qkv[base + 512];
    }
    float att[4][4];
#pragma unroll
    for (int s = 0; s < 4; ++s)
#pragma unroll
        for (int t = 0; t < 4; ++t) {
            float p = q[s] * k[t];
#pragma unroll
            for (int off = 32; off > 0; off >>= 1) p += __shfl_xor(p, off);
            att[s][t] = p * 0.125f;   // 1/sqrt(64)
        }
#pragma unroll
    for (int s = 0; s < 4; ++s) {
        float mx = fmaxf(fmaxf(att[s][0], att[s][1]), fmaxf(att[s][2], att[s][3]));
        float e0 = expf(att[s][0] - mx), e1 = expf(att[s][1] - mx);
        float e2 = expf(att[s][2] - mx), e3 = expf(att[s][3] - mx);
        float inv = 1.f / (e0 + e1 + e2 + e3);
        float ov = (e0 * vv[0] + e1 * vv[1] + e2 * vv[2] + e3 * vv[3]) * inv;
        o[(size_t)(s * kN + n) * kD + h * 64 + d] = ov;
    }
}

// ---- Vmean[v][d] = mean_m Vn[v][m][d] ------------------------------------
__global__ __launch_bounds__(1024) void vmean_kernel(const __bf16* __restrict__ Vn,
                                                     float* __restrict__ Vmean)
{
    int v = blockIdx.x;
    int d = threadIdx.x & 255, c = threadIdx.x >> 8;
    __shared__ float part[4][256];
    float s = 0.f;
    for (int m = c * 384; m < (c + 1) * 384; ++m)
        s += (float)Vn[((size_t)v * kN + m) * kD + d];
    part[c][d] = s;
    __syncthreads();
    if (c == 0)
        Vmean[v * kD + d] = (part[0][d] + part[1][d] + part[2][d] + part[3][d]) * (1.f / 1536.f);
}

// ---- exact top-32 per C row (p!=q), jax tie rule (lowest index) ----------
__global__ __launch_bounds__(256) void topk_kernel(const float* __restrict__ C,
                                                   int* __restrict__ idxOut,
                                                   int* __restrict__ cntOut)
{
    int n  = blockIdx.x;
    int pi = blockIdx.y;            // 0..11
    int p  = pi / 3;
    int qi = pi % 3;
    int q  = qi + (qi >= p ? 1 : 0);
    __shared__ float vals[kN];
    __shared__ float rv[4];
    __shared__ int   ri[4];
    int tid = threadIdx.x;
    const float* row = C + ((size_t)((p * kV + q) * kN + n)) * kN;
    for (int i = tid; i < kN; i += 256) vals[i] = row[i];
    __syncthreads();
    int cnt = 0;
    for (int it = 0; it < kTopK; ++it) {
        float bv = -1e30f; int bi = 0;
        for (int i = tid; i < kN; i += 256) {
            float v = vals[i];
            if (v > bv) { bv = v; bi = i; }   // ascending scan: ties keep lower idx
        }
        for (int off = 32; off > 0; off >>= 1) {
            float ov = __shfl_xor(bv, off);
            int   oi = __shfl_xor(bi, off);
            if (ov > bv || (ov == bv && oi < bi)) { bv = ov; bi = oi; }
        }
        if ((tid & 63) == 0) { rv[tid >> 6] = bv; ri[tid >> 6] = bi; }
        __syncthreads();
        if (tid == 0) {
            for (int w2 = 1; w2 < 4; ++w2)
                if (rv[w2] > bv || (rv[w2] == bv && ri[w2] < bi)) { bv = rv[w2]; bi = ri[w2]; }
            vals[bi] = -1e30f;
            if (bv > 0.f) { idxOut[((size_t)(p * kV + q) * kN + n) * kTopK + it] = bi; cnt++; }
        }
        __syncthreads();
    }
    if (tid == 0) cntOut[(p * kV + q) * kN + n] = cnt;
}

// ---- scores + per-(p,q) softmax + V gather + final fuse ------------------
__global__ __launch_bounds__(256) void fuse_kernel(
    const __bf16* __restrict__ Qn, const __bf16* __restrict__ Kn,
    const __bf16* __restrict__ Vn, const float* __restrict__ Vmean,
    const int* __restrict__ idxBuf, const int* __restrict__ cntBuf,
    const float* __restrict__ alignedF, const float* __restrict__ H,
    const float* __restrict__ alpha_align, const float* __restrict__ beta,
    float* __restrict__ out)
{
    int n = blockIdx.x, p = blockIdx.y, tid = threadIdx.x;
    __shared__ float qsh[kD];
    __shared__ float wsh[96];
    __shared__ int   msh[96];
    __shared__ int   qvsh[96];
    qsh[tid] = (float)Qn[((size_t)p * kN + n) * kD + tid];
    __syncthreads();
    if (tid < 96) {
        int g = tid >> 5, r = tid & 31;
        int q = g + (g >= p ? 1 : 0);
        int cnt = cntBuf[(p * kV + q) * kN + n];
        float sc = -1e30f; int m = 0;
        if (r < cnt) {
            m = idxBuf[((size_t)(p * kV + q) * kN + n) * kTopK + r];
            const __bf16* kr = Kn + ((size_t)q * kN + m) * kD;
            float s = 0.f;
            for (int dd = 0; dd < kD; dd += 8) {
                bf16x8 kv = *(const bf16x8*)(kr + dd);
                f32x4 q0 = *(const f32x4*)&qsh[dd];
                f32x4 q1 = *(const f32x4*)&qsh[dd + 4];
                s += q0[0]*(float)kv[0] + q0[1]*(float)kv[1] + q0[2]*(float)kv[2] + q0[3]*(float)kv[3]
                   + q1[0]*(float)kv[4] + q1[1]*(float)kv[5] + q1[2]*(float)kv[6] + q1[3]*(float)kv[7];
            }
            sc = s * 0.0625f;   // 1/sqrt(256)
        }
        float mx = sc;
        for (int off = 16; off > 0; off >>= 1) mx = fmaxf(mx, __shfl_xor(mx, off, 32));
        float e = (r < cnt) ? expf(sc - mx) : 0.f;
        float ssum = e;
        for (int off = 16; off > 0; off >>= 1) ssum += __shfl_xor(ssum, off, 32);
        wsh[tid]  = (ssum > 0.f) ? e / ssum : 0.f;
        msh[tid]  = m;
        qvsh[tid] = q;
    }
    __syncthreads();
    float acc = Vmean[p * kD + tid];        // q==p uniform-softmax term
    for (int j = 0; j < 96; ++j) {
        float w = wsh[j];
        if (w != 0.f)
            acc += w * (float)Vn[((size_t)qvsh[j] * kN + msh[j]) * kD + tid];
    }
    float aa = 1.f / (1.f + expf(-alpha_align[0]));
    float bt = beta[0];
    size_t off = ((size_t)p * kN + n) * kD + tid;
    float al = alignedF[off];
    float f  = fmaxf(aa * al + (1.f - aa) * acc, 0.f);
    out[off] = H[off] * bt + (1.f - bt) * f;
}

extern "C" void kernel_launch(void* const* d_in, const int* in_sizes, int n_in,
                              void* d_out, int out_size, void* d_ws, size_t ws_size,
                              hipStream_t stream)
{
    const float* H        = (const float*)d_in[0];
    const float* C        = (const float*)d_in[1];
    const float* WQ       = (const float*)d_in[2];
    const float* WK       = (const float*)d_in[3];
    const float* WV       = (const float*)d_in[4];
    const float* inW      = (const float*)d_in[5];
    const float* inB      = (const float*)d_in[6];
    const float* outW     = (const float*)d_in[7];
    const float* outBias  = (const float*)d_in[8];
    const float* alphas   = (const float*)d_in[9];
    const float* alpha_al = (const float*)d_in[10];
    const float* beta     = (const float*)d_in[11];
    float* out = (float*)d_out;

    char* w = (char*)d_ws;
    __bf16* qkv      = (__bf16*)w;  w += (size_t)6144 * 768 * 2;   // 9.4 MB
    float*  o        = (float*)w;   w += (size_t)6144 * 256 * 4;   // 6.3 MB
    float*  alignedF = (float*)w;   w += (size_t)6144 * 256 * 4;   // 6.3 MB
    __bf16* Qn       = (__bf16*)w;  w += (size_t)6144 * 256 * 2;   // 3.1 MB
    __bf16* Kn       = (__bf16*)w;  w += (size_t)6144 * 256 * 2;
    __bf16* Vn       = (__bf16*)w;  w += (size_t)6144 * 256 * 2;
    float*  Vmean    = (float*)w;   w += (size_t)4 * 256 * 4;
    int*    idxBuf   = (int*)w;     w += (size_t)16 * 1536 * 32 * 4; // 3.1 MB
    int*    cntBuf   = (int*)w;                                      // 0.1 MB

    // 1) qkv = H @ inW^T + inB     (6144 x 768 x 256) -> bf16
    gemm_bt_kernel<<<4608, 256, 0, stream>>>(H, inW, inB, 6144, 768, 256,
        0, 0, 0, qkv, nullptr, nullptr, nullptr, 0);
    // 2) 4x4 attention per (n,h) -> o (f32)
    attn_kernel<<<1536, 256, 0, stream>>>(qkv, o);
    // 3) aligned = alphas*(o @ outW^T + b) + (1-alphas)*H -> f32
    gemm_bt_kernel<<<1536, 256, 0, stream>>>(o, outW, outBias, 6144, 256, 256,
        0, 0, 1, nullptr, alignedF, H, alphas, 1536);
    // 4) stage-2 projections (per-view weights) -> bf16
    gemm_bt_kernel<<<1536, 256, 0, stream>>>(alignedF, WQ, nullptr, 6144, 256, 256,
        1536, 256 * 256, 0, Qn, nullptr, nullptr, nullptr, 0);
    gemm_bt_kernel<<<1536, 256, 0, stream>>>(alignedF, WK, nullptr, 6144, 256, 256,
        1536, 256 * 256, 0, Kn, nullptr, nullptr, nullptr, 0);
    gemm_bt_kernel<<<1536, 256, 0, stream>>>(alignedF, WV, nullptr, 6144, 256, 256,
        1536, 256 * 256, 0, Vn, nullptr, nullptr, nullptr, 0);
    // 5) Vmean (q==p uniform softmax term)
    vmean_kernel<<<4, 1024, 0, stream>>>(Vn, Vmean);
    // 6) top-32 of each C row, p != q only
    topk_kernel<<<dim3(1536, 12), 256, 0, stream>>>(C, idxBuf, cntBuf);
    // 7) scores + softmax + gather + fuse -> out
    fuse_kernel<<<dim3(1536, 4), 256, 0, stream>>>(Qn, Kn, Vn, Vmean, idxBuf, cntBuf,
        alignedF, H, alpha_al, beta, out);
}

// Round 3
// 641.613 us; speedup vs baseline: 1.6338x; 1.6338x over previous
//
#include <hip/hip_runtime.h>
#include <hip/hip_bf16.h>
#include <math.h>

typedef __bf16 bf16x8 __attribute__((ext_vector_type(8)));
typedef float  f32x4  __attribute__((ext_vector_type(4)));

static constexpr int kV = 4;
static constexpr int kN = 1536;
static constexpr int kD = 256;
static constexpr int kTopK = 32;

// ---- GEMM (B^T form): out[m][n] = sum_k A[m][k]*B[n][k] (+bias[n]) --------
// Wave tile: 16 (M) x 64 (N) — A fragment reused across 4 N-tiles.
// mode 0: plain bf16 write. mode 1: blend a*(v+bias)+(1-a)*H -> f32 out.
__global__ __launch_bounds__(256) void gemm_bt_kernel(
    const float* __restrict__ A, const float* __restrict__ Bm,
    const float* __restrict__ bias, int M, int Nc, int K,
    int bBatchRows, int bBatchStride, int mode,
    __bf16* __restrict__ outB, float* __restrict__ outF,
    const float* __restrict__ Hres, const float* __restrict__ alphas,
    int rowsPerView)
{
    int wave = blockIdx.x * (blockDim.x >> 6) + (threadIdx.x >> 6);
    int tilesN4 = Nc >> 6;              // groups of 4 adjacent 16-col tiles
    int tm  = wave / tilesN4;
    int tn4 = wave - tm * tilesN4;
    if ((tm << 4) >= M) return;
    int lane = threadIdx.x & 63;
    int r    = lane & 15;               // A row / B row (=output col)
    int quad = lane >> 4;               // k-chunk selector
    const float* Ap = A + (size_t)((tm << 4) + r) * K + quad * 8;
    const float* Bp = Bm + (size_t)((tn4 << 6) + r) * K + quad * 8;
    if (bBatchRows > 0) Bp += (size_t)(((tm << 4)) / bBatchRows) * bBatchStride;
    f32x4 acc[4] = {{0.f,0.f,0.f,0.f},{0.f,0.f,0.f,0.f},{0.f,0.f,0.f,0.f},{0.f,0.f,0.f,0.f}};
    for (int k0 = 0; k0 < K; k0 += 32) {
        f32x4 a0 = *(const f32x4*)(Ap + k0);
        f32x4 a1 = *(const f32x4*)(Ap + k0 + 4);
        bf16x8 a;
#pragma unroll
        for (int j = 0; j < 4; ++j) { a[j] = (__bf16)a0[j]; a[j + 4] = (__bf16)a1[j]; }
#pragma unroll
        for (int t = 0; t < 4; ++t) {
            const float* bp = Bp + (size_t)(t * 16) * K + k0;
            f32x4 b0 = *(const f32x4*)bp;
            f32x4 b1 = *(const f32x4*)(bp + 4);
            bf16x8 b;
#pragma unroll
            for (int j = 0; j < 4; ++j) { b[j] = (__bf16)b0[j]; b[j + 4] = (__bf16)b1[j]; }
            acc[t] = __builtin_amdgcn_mfma_f32_16x16x32_bf16(a, b, acc[t], 0, 0, 0);
        }
    }
#pragma unroll
    for (int t = 0; t < 4; ++t) {
        int gn = (tn4 << 6) + t * 16 + r;    // C/D: col = lane&15
        float bv = bias ? bias[gn] : 0.f;
#pragma unroll
        for (int i = 0; i < 4; ++i) {
            int gm = (tm << 4) + quad * 4 + i;   // C/D: row = quad*4+reg
            float v = acc[t][i] + bv;
            size_t off = (size_t)gm * Nc + gn;
            if (mode == 0) {
                outB[off] = (__bf16)v;
            } else {
                float a_ = alphas[gm / rowsPerView];
                float h  = Hres[off];
                outF[off] = a_ * v + (1.f - a_) * h;
            }
        }
    }
}

// ---- tiny 4x4 attention per (n,h); wave = one head, lane = d -------------
__global__ __launch_bounds__(256) void attn_kernel(const __bf16* __restrict__ qkv,
                                                   float* __restrict__ o)
{
    int n = blockIdx.x;
    int h = threadIdx.x >> 6;
    int d = threadIdx.x & 63;
    float q[4], k[4], vv[4];
#pragma unroll
    for (int s = 0; s < 4; ++s) {
        size_t base = (size_t)(s * kN + n) * 768 + h * 64 + d;
        q[s]  = (float)qkv[base];
        k[s]  = (float)qkv[base + 256];
        vv[s] = (float)qkv[base + 512];
    }
    float att[4][4];
#pragma unroll
    for (int s = 0; s < 4; ++s)
#pragma unroll
        for (int t = 0; t < 4; ++t) {
            float p = q[s] * k[t];
#pragma unroll
            for (int off = 32; off > 0; off >>= 1) p += __shfl_xor(p, off);
            att[s][t] = p * 0.125f;   // 1/sqrt(64)
        }
#pragma unroll
    for (int s = 0; s < 4; ++s) {
        float mx = fmaxf(fmaxf(att[s][0], att[s][1]), fmaxf(att[s][2], att[s][3]));
        float e0 = expf(att[s][0] - mx), e1 = expf(att[s][1] - mx);
        float e2 = expf(att[s][2] - mx), e3 = expf(att[s][3] - mx);
        float inv = 1.f / (e0 + e1 + e2 + e3);
        float ov = (e0 * vv[0] + e1 * vv[1] + e2 * vv[2] + e3 * vv[3]) * inv;
        o[(size_t)(s * kN + n) * kD + h * 64 + d] = ov;
    }
}

// ---- Vmean[v][d] = mean_m Vn[v][m][d] ------------------------------------
__global__ __launch_bounds__(1024) void vmean_kernel(const __bf16* __restrict__ Vn,
                                                     float* __restrict__ Vmean)
{
    int v = blockIdx.x;
    int d = threadIdx.x & 255, c = threadIdx.x >> 8;
    __shared__ float part[4][256];
    float s = 0.f;
    for (int m = c * 384; m < (c + 1) * 384; ++m)
        s += (float)Vn[((size_t)v * kN + m) * kD + d];
    part[c][d] = s;
    __syncthreads();
    if (c == 0)
        Vmean[v * kD + d] = (part[0][d] + part[1][d] + part[2][d] + part[3][d]) * (1.f / 1536.f);
}

// ---- exact top-32 per C row (p!=q) via 8-bit radix select ----------------
// jax tie rule: among values equal to the threshold, lowest index wins.
__global__ __launch_bounds__(256) void topk_kernel(const float* __restrict__ C,
                                                   int* __restrict__ idxOut,
                                                   int* __restrict__ cntOut)
{
    int n  = blockIdx.x;
    int pi = blockIdx.y;            // 0..11
    int p  = pi / 3;
    int qi = pi % 3;
    int q  = qi + (qi >= p ? 1 : 0);
    int tid = threadIdx.x;
    __shared__ unsigned int keys[kN];
    __shared__ unsigned int hist[256];
    __shared__ unsigned int s_bin, s_above, s_cnt;
    const float* row = C + ((size_t)((p * kV + q) * kN + n)) * kN;
    // coalesced load + order-preserving f32->u32 transform
#pragma unroll
    for (int j = 0; j < 6; ++j) {
        int i = tid + j * 256;
        unsigned int u = __float_as_uint(row[i]);
        keys[i] = (u & 0x80000000u) ? ~u : (u | 0x80000000u);
    }
    if (tid == 0) s_cnt = 0;
    __syncthreads();

    unsigned int pref = 0;
    unsigned int need = kTopK;
#pragma unroll
    for (int pass = 0; pass < 4; ++pass) {
        const int shift = 24 - 8 * pass;
        hist[tid] = 0;
        __syncthreads();
#pragma unroll
        for (int j = 0; j < 6; ++j) {
            unsigned int k = keys[tid * 6 + j];
            bool match = (pass == 0) || (((k ^ pref) >> (shift + 8)) == 0);
            if (match) atomicAdd(&hist[(k >> shift) & 255u], 1u);
        }
        __syncthreads();
        if (tid < 64) {
            int lane = tid;
            unsigned int h0 = hist[lane*4+0], h1 = hist[lane*4+1];
            unsigned int h2 = hist[lane*4+2], h3 = hist[lane*4+3];
            unsigned int s3 = h3, s2 = h2 + s3, s1 = h1 + s2, s0 = h0 + s1;
            unsigned int run = s0;
#pragma unroll
            for (int off = 1; off < 64; off <<= 1) {
                unsigned int v = __shfl_down(run, off);
                if (lane + off < 64) run += v;
            }
            unsigned int above = run - s0;   // strict suffix over lane totals
            unsigned int suf[4]  = {above+s0, above+s1, above+s2, above+s3};
            unsigned int sufN[4] = {above+s1, above+s2, above+s3, above};
#pragma unroll
            for (int k2 = 0; k2 < 4; ++k2)
                if (suf[k2] >= need && sufN[k2] < need) {
                    s_bin = (unsigned int)(lane*4 + k2); s_above = sufN[k2];
                }
        }
        __syncthreads();
        pref |= s_bin << shift;
        need -= s_above;
        __syncthreads();
    }
    unsigned int T = pref;   // exact 32-bit threshold key; `need` = #equals to take
    // exclusive prefix of per-thread equal-counts (blocked layout => index order)
    unsigned int eq = 0;
#pragma unroll
    for (int j = 0; j < 6; ++j) eq += (keys[tid * 6 + j] == T) ? 1u : 0u;
    hist[tid] = eq;
    __syncthreads();
    if (tid < 64) {
        int lane = tid;
        unsigned int e0 = hist[lane*4+0], e1 = hist[lane*4+1];
        unsigned int e2 = hist[lane*4+2], e3 = hist[lane*4+3];
        unsigned int tot = e0 + e1 + e2 + e3;
        unsigned int run = tot;
#pragma unroll
        for (int off = 1; off < 64; off <<= 1) {
            unsigned int v = __shfl_up(run, off);
            if (lane >= off) run += v;
        }
        unsigned int base = run - tot;  // exclusive prefix over lane totals
        hist[lane*4+0] = base;
        hist[lane*4+1] = base + e0;
        hist[lane*4+2] = base + e0 + e1;
        hist[lane*4+3] = base + e0 + e1 + e2;
    }
    __syncthreads();
    unsigned int myBase = hist[tid];
    int outBase = ((p * kV + q) * kN + n) * kTopK;
    unsigned int eqSeen = 0;
#pragma unroll
    for (int j = 0; j < 6; ++j) {
        int i = tid * 6 + j;
        unsigned int k = keys[i];
        bool take = (k > T);
        if (k == T) { take = (myBase + eqSeen < need); eqSeen++; }
        if (take && k > 0x80000000u) {      // value > 0 filter
            unsigned int pos = atomicAdd(&s_cnt, 1u);
            idxOut[outBase + pos] = i;
        }
    }
    __syncthreads();
    if (tid == 0) cntOut[(p * kV + q) * kN + n] = (int)s_cnt;
}

// ---- scores + per-(p,q) softmax + V gather + final fuse ------------------
__global__ __launch_bounds__(256) void fuse_kernel(
    const __bf16* __restrict__ Qn, const __bf16* __restrict__ Kn,
    const __bf16* __restrict__ Vn, const float* __restrict__ Vmean,
    const int* __restrict__ idxBuf, const int* __restrict__ cntBuf,
    const float* __restrict__ alignedF, const float* __restrict__ H,
    const float* __restrict__ alpha_align, const float* __restrict__ beta,
    float* __restrict__ out)
{
    int n = blockIdx.x, p = blockIdx.y, tid = threadIdx.x;
    __shared__ float qsh[kD];
    __shared__ float wsh[96];
    __shared__ int   msh[96];
    __shared__ int   qvsh[96];
    qsh[tid] = (float)Qn[((size_t)p * kN + n) * kD + tid];
    __syncthreads();
    if (tid < 96) {
        int g = tid >> 5, r = tid & 31;
        int q = g + (g >= p ? 1 : 0);
        int cnt = cntBuf[(p * kV + q) * kN + n];
        float sc = -1e30f; int m = 0;
        if (r < cnt) {
            m = idxBuf[((size_t)(p * kV + q) * kN + n) * kTopK + r];
            const __bf16* kr = Kn + ((size_t)q * kN + m) * kD;
            float s = 0.f;
            for (int dd = 0; dd < kD; dd += 8) {
                bf16x8 kv = *(const bf16x8*)(kr + dd);
                f32x4 q0 = *(const f32x4*)&qsh[dd];
                f32x4 q1 = *(const f32x4*)&qsh[dd + 4];
                s += q0[0]*(float)kv[0] + q0[1]*(float)kv[1] + q0[2]*(float)kv[2] + q0[3]*(float)kv[3]
                   + q1[0]*(float)kv[4] + q1[1]*(float)kv[5] + q1[2]*(float)kv[6] + q1[3]*(float)kv[7];
            }
            sc = s * 0.0625f;   // 1/sqrt(256)
        }
        float mx = sc;
        for (int off = 16; off > 0; off >>= 1) mx = fmaxf(mx, __shfl_xor(mx, off, 32));
        float e = (r < cnt) ? expf(sc - mx) : 0.f;
        float ssum = e;
        for (int off = 16; off > 0; off >>= 1) ssum += __shfl_xor(ssum, off, 32);
        wsh[tid]  = (ssum > 0.f) ? e / ssum : 0.f;
        msh[tid]  = m;
        qvsh[tid] = q;
    }
    __syncthreads();
    float acc = Vmean[p * kD + tid];        // q==p uniform-softmax term
    for (int j = 0; j < 96; ++j) {
        float w = wsh[j];
        if (w != 0.f)
            acc += w * (float)Vn[((size_t)qvsh[j] * kN + msh[j]) * kD + tid];
    }
    float aa = 1.f / (1.f + expf(-alpha_align[0]));
    float bt = beta[0];
    size_t off = ((size_t)p * kN + n) * kD + tid;
    float al = alignedF[off];
    float f  = fmaxf(aa * al + (1.f - aa) * acc, 0.f);
    out[off] = H[off] * bt + (1.f - bt) * f;
}

extern "C" void kernel_launch(void* const* d_in, const int* in_sizes, int n_in,
                              void* d_out, int out_size, void* d_ws, size_t ws_size,
                              hipStream_t stream)
{
    const float* H        = (const float*)d_in[0];
    const float* C        = (const float*)d_in[1];
    const float* WQ       = (const float*)d_in[2];
    const float* WK       = (const float*)d_in[3];
    const float* WV       = (const float*)d_in[4];
    const float* inW      = (const float*)d_in[5];
    const float* inB      = (const float*)d_in[6];
    const float* outW     = (const float*)d_in[7];
    const float* outBias  = (const float*)d_in[8];
    const float* alphas   = (const float*)d_in[9];
    const float* alpha_al = (const float*)d_in[10];
    const float* beta     = (const float*)d_in[11];
    float* out = (float*)d_out;

    char* w = (char*)d_ws;
    __bf16* qkv      = (__bf16*)w;  w += (size_t)6144 * 768 * 2;   // 9.4 MB
    float*  o        = (float*)w;   w += (size_t)6144 * 256 * 4;   // 6.3 MB
    float*  alignedF = (float*)w;   w += (size_t)6144 * 256 * 4;   // 6.3 MB
    __bf16* Qn       = (__bf16*)w;  w += (size_t)6144 * 256 * 2;   // 3.1 MB
    __bf16* Kn       = (__bf16*)w;  w += (size_t)6144 * 256 * 2;
    __bf16* Vn       = (__bf16*)w;  w += (size_t)6144 * 256 * 2;
    float*  Vmean    = (float*)w;   w += (size_t)4 * 256 * 4;
    int*    idxBuf   = (int*)w;     w += (size_t)16 * 1536 * 32 * 4; // 3.1 MB
    int*    cntBuf   = (int*)w;                                      // 0.1 MB

    // 1) qkv = H @ inW^T + inB (6144 x 768 x 256) -> bf16.  waves = 384*12
    gemm_bt_kernel<<<1152, 256, 0, stream>>>(H, inW, inB, 6144, 768, 256,
        0, 0, 0, qkv, nullptr, nullptr, nullptr, 0);
    // 2) 4x4 attention per (n,h) -> o (f32)
    attn_kernel<<<1536, 256, 0, stream>>>(qkv, o);
    // 3) aligned = alphas*(o @ outW^T + b) + (1-alphas)*H -> f32. waves = 384*4
    gemm_bt_kernel<<<384, 256, 0, stream>>>(o, outW, outBias, 6144, 256, 256,
        0, 0, 1, nullptr, alignedF, H, alphas, 1536);
    // 4) stage-2 projections (per-view weights) -> bf16
    gemm_bt_kernel<<<384, 256, 0, stream>>>(alignedF, WQ, nullptr, 6144, 256, 256,
        1536, 256 * 256, 0, Qn, nullptr, nullptr, nullptr, 0);
    gemm_bt_kernel<<<384, 256, 0, stream>>>(alignedF, WK, nullptr, 6144, 256, 256,
        1536, 256 * 256, 0, Kn, nullptr, nullptr, nullptr, 0);
    gemm_bt_kernel<<<384, 256, 0, stream>>>(alignedF, WV, nullptr, 6144, 256, 256,
        1536, 256 * 256, 0, Vn, nullptr, nullptr, nullptr, 0);
    // 5) Vmean (q==p uniform softmax term)
    vmean_kernel<<<4, 1024, 0, stream>>>(Vn, Vmean);
    // 6) top-32 of each C row, p != q only (radix select)
    topk_kernel<<<dim3(1536, 12), 256, 0, stream>>>(C, idxBuf, cntBuf);
    // 7) scores + softmax + gather + fuse -> out
    fuse_kernel<<<dim3(1536, 4), 256, 0, stream>>>(Qn, Kn, Vn, Vmean, idxBuf, cntBuf,
        alignedF, H, alpha_al, beta, out);
}

// Round 4
// 488.144 us; speedup vs baseline: 2.1474x; 1.3144x over previous
//
#include <hip/hip_runtime.h>
#include <hip/hip_bf16.h>
#include <math.h>

typedef __bf16 bf16x8 __attribute__((ext_vector_type(8)));
typedef __bf16 bf16x4 __attribute__((ext_vector_type(4)));
typedef float  f32x4  __attribute__((ext_vector_type(4)));

static constexpr int kV = 4;
static constexpr int kN = 1536;
static constexpr int kD = 256;
static constexpr int kTopK = 32;

// ---- GEMM (B^T form): out[m][n] = sum_k A[m][k]*B[n][k] (+bias[n]) --------
// Wave tile: 16 (M) x 64 (N) — A fragment reused across 4 N-tiles.
// mode 0: plain bf16 write. mode 1: blend a*(v+bias)+(1-a)*H -> f32 out.
__global__ __launch_bounds__(256) void gemm_bt_kernel(
    const float* __restrict__ A, const float* __restrict__ Bm,
    const float* __restrict__ bias, int M, int Nc, int K,
    int mode,
    __bf16* __restrict__ outB, float* __restrict__ outF,
    const float* __restrict__ Hres, const float* __restrict__ alphas,
    int rowsPerView)
{
    int wave = blockIdx.x * (blockDim.x >> 6) + (threadIdx.x >> 6);
    int tilesN4 = Nc >> 6;              // groups of 4 adjacent 16-col tiles
    int tm  = wave / tilesN4;
    int tn4 = wave - tm * tilesN4;
    if ((tm << 4) >= M) return;
    int lane = threadIdx.x & 63;
    int r    = lane & 15;               // A row / B row (=output col)
    int quad = lane >> 4;               // k-chunk selector
    const float* Ap = A + (size_t)((tm << 4) + r) * K + quad * 8;
    const float* Bp = Bm + (size_t)((tn4 << 6) + r) * K + quad * 8;
    f32x4 acc[4] = {{0.f,0.f,0.f,0.f},{0.f,0.f,0.f,0.f},{0.f,0.f,0.f,0.f},{0.f,0.f,0.f,0.f}};
    for (int k0 = 0; k0 < K; k0 += 32) {
        f32x4 a0 = *(const f32x4*)(Ap + k0);
        f32x4 a1 = *(const f32x4*)(Ap + k0 + 4);
        bf16x8 a;
#pragma unroll
        for (int j = 0; j < 4; ++j) { a[j] = (__bf16)a0[j]; a[j + 4] = (__bf16)a1[j]; }
#pragma unroll
        for (int t = 0; t < 4; ++t) {
            const float* bp = Bp + (size_t)(t * 16) * K + k0;
            f32x4 b0 = *(const f32x4*)bp;
            f32x4 b1 = *(const f32x4*)(bp + 4);
            bf16x8 b;
#pragma unroll
            for (int j = 0; j < 4; ++j) { b[j] = (__bf16)b0[j]; b[j + 4] = (__bf16)b1[j]; }
            acc[t] = __builtin_amdgcn_mfma_f32_16x16x32_bf16(a, b, acc[t], 0, 0, 0);
        }
    }
#pragma unroll
    for (int t = 0; t < 4; ++t) {
        int gn = (tn4 << 6) + t * 16 + r;    // C/D: col = lane&15
        float bv = bias ? bias[gn] : 0.f;
#pragma unroll
        for (int i = 0; i < 4; ++i) {
            int gm = (tm << 4) + quad * 4 + i;   // C/D: row = quad*4+reg
            float v = acc[t][i] + bv;
            size_t off = (size_t)gm * Nc + gn;
            if (mode == 0) {
                outB[off] = (__bf16)v;
            } else {
                float a_ = alphas[gm / rowsPerView];
                float h  = Hres[off];
                outF[off] = a_ * v + (1.f - a_) * h;
            }
        }
    }
}

// ---- stage-2 Q/K/V projections, one launch (blockIdx.y selects W / out) --
__global__ __launch_bounds__(256) void gemm_qkv3_kernel(
    const float* __restrict__ A,
    const float* __restrict__ W0, const float* __restrict__ W1, const float* __restrict__ W2,
    __bf16* __restrict__ O0, __bf16* __restrict__ O1, __bf16* __restrict__ O2)
{
    const float* Bm = (blockIdx.y == 0) ? W0 : (blockIdx.y == 1) ? W1 : W2;
    __bf16*      Ob = (blockIdx.y == 0) ? O0 : (blockIdx.y == 1) ? O1 : O2;
    const int K = kD, Nc = kD;
    int wave = blockIdx.x * 4 + (threadIdx.x >> 6);
    int tilesN4 = Nc >> 6;
    int tm  = wave / tilesN4;
    int tn4 = wave - tm * tilesN4;
    int lane = threadIdx.x & 63;
    int r    = lane & 15;
    int quad = lane >> 4;
    const float* Ap = A + (size_t)((tm << 4) + r) * K + quad * 8;
    const float* Bp = Bm + (size_t)((tn4 << 6) + r) * K + quad * 8
                      + (size_t)((tm << 4) / kN) * kD * kD;   // per-view W
    f32x4 acc[4] = {{0.f,0.f,0.f,0.f},{0.f,0.f,0.f,0.f},{0.f,0.f,0.f,0.f},{0.f,0.f,0.f,0.f}};
    for (int k0 = 0; k0 < K; k0 += 32) {
        f32x4 a0 = *(const f32x4*)(Ap + k0);
        f32x4 a1 = *(const f32x4*)(Ap + k0 + 4);
        bf16x8 a;
#pragma unroll
        for (int j = 0; j < 4; ++j) { a[j] = (__bf16)a0[j]; a[j + 4] = (__bf16)a1[j]; }
#pragma unroll
        for (int t = 0; t < 4; ++t) {
            const float* bp = Bp + (size_t)(t * 16) * K + k0;
            f32x4 b0 = *(const f32x4*)bp;
            f32x4 b1 = *(const f32x4*)(bp + 4);
            bf16x8 b;
#pragma unroll
            for (int j = 0; j < 4; ++j) { b[j] = (__bf16)b0[j]; b[j + 4] = (__bf16)b1[j]; }
            acc[t] = __builtin_amdgcn_mfma_f32_16x16x32_bf16(a, b, acc[t], 0, 0, 0);
        }
    }
#pragma unroll
    for (int t = 0; t < 4; ++t) {
        int gn = (tn4 << 6) + t * 16 + r;
#pragma unroll
        for (int i = 0; i < 4; ++i) {
            int gm = (tm << 4) + quad * 4 + i;
            Ob[(size_t)gm * Nc + gn] = (__bf16)acc[t][i];
        }
    }
}

// ---- tiny 4x4 attention per (n,h); wave = one head, lane = d -------------
__global__ __launch_bounds__(256) void attn_kernel(const __bf16* __restrict__ qkv,
                                                   float* __restrict__ o)
{
    int n = blockIdx.x;
    int h = threadIdx.x >> 6;
    int d = threadIdx.x & 63;
    float q[4], k[4], vv[4];
#pragma unroll
    for (int s = 0; s < 4; ++s) {
        size_t base = (size_t)(s * kN + n) * 768 + h * 64 + d;
        q[s]  = (float)qkv[base];
        k[s]  = (float)qkv[base + 256];
        vv[s] = (float)qkv[base + 512];
    }
    float att[4][4];
#pragma unroll
    for (int s = 0; s < 4; ++s)
#pragma unroll
        for (int t = 0; t < 4; ++t) {
            float p = q[s] * k[t];
#pragma unroll
            for (int off = 32; off > 0; off >>= 1) p += __shfl_xor(p, off);
            att[s][t] = p * 0.125f;   // 1/sqrt(64)
        }
#pragma unroll
    for (int s = 0; s < 4; ++s) {
        float mx = fmaxf(fmaxf(att[s][0], att[s][1]), fmaxf(att[s][2], att[s][3]));
        float e0 = expf(att[s][0] - mx), e1 = expf(att[s][1] - mx);
        float e2 = expf(att[s][2] - mx), e3 = expf(att[s][3] - mx);
        float inv = 1.f / (e0 + e1 + e2 + e3);
        float ov = (e0 * vv[0] + e1 * vv[1] + e2 * vv[2] + e3 * vv[3]) * inv;
        o[(size_t)(s * kN + n) * kD + h * 64 + d] = ov;
    }
}

// ---- Vmean[v][d] = mean_m Vn[v][m][d] ------------------------------------
__global__ __launch_bounds__(1024) void vmean_kernel(const __bf16* __restrict__ Vn,
                                                     float* __restrict__ Vmean)
{
    int v = blockIdx.x;
    int d = threadIdx.x & 255, c = threadIdx.x >> 8;
    __shared__ float part[4][256];
    float s = 0.f;
    for (int m = c * 384; m < (c + 1) * 384; ++m)
        s += (float)Vn[((size_t)v * kN + m) * kD + d];
    part[c][d] = s;
    __syncthreads();
    if (c == 0)
        Vmean[v * kD + d] = (part[0][d] + part[1][d] + part[2][d] + part[3][d]) * (1.f / 1536.f);
}

// ---- exact top-32 per C row (p!=q) via 8-bit radix select ----------------
__global__ __launch_bounds__(256) void topk_kernel(const float* __restrict__ C,
                                                   int* __restrict__ idxOut,
                                                   int* __restrict__ cntOut)
{
    int n  = blockIdx.x;
    int pi = blockIdx.y;            // 0..11
    int p  = pi / 3;
    int qi = pi % 3;
    int q  = qi + (qi >= p ? 1 : 0);
    int tid = threadIdx.x;
    __shared__ unsigned int keys[kN];
    __shared__ unsigned int hist[256];
    __shared__ unsigned int s_bin, s_above, s_cnt;
    const float* row = C + ((size_t)((p * kV + q) * kN + n)) * kN;
#pragma unroll
    for (int j = 0; j < 6; ++j) {
        int i = tid + j * 256;
        unsigned int u = __float_as_uint(row[i]);
        keys[i] = (u & 0x80000000u) ? ~u : (u | 0x80000000u);
    }
    if (tid == 0) s_cnt = 0;
    __syncthreads();

    unsigned int pref = 0;
    unsigned int need = kTopK;
#pragma unroll
    for (int pass = 0; pass < 4; ++pass) {
        const int shift = 24 - 8 * pass;
        hist[tid] = 0;
        __syncthreads();
#pragma unroll
        for (int j = 0; j < 6; ++j) {
            unsigned int k = keys[tid * 6 + j];
            bool match = (pass == 0) || (((k ^ pref) >> (shift + 8)) == 0);
            if (match) atomicAdd(&hist[(k >> shift) & 255u], 1u);
        }
        __syncthreads();
        if (tid < 64) {
            int lane = tid;
            unsigned int h0 = hist[lane*4+0], h1 = hist[lane*4+1];
            unsigned int h2 = hist[lane*4+2], h3 = hist[lane*4+3];
            unsigned int s3 = h3, s2 = h2 + s3, s1 = h1 + s2, s0 = h0 + s1;
            unsigned int run = s0;
#pragma unroll
            for (int off = 1; off < 64; off <<= 1) {
                unsigned int v = __shfl_down(run, off);
                if (lane + off < 64) run += v;
            }
            unsigned int above = run - s0;   // strict suffix over lane totals
            unsigned int suf[4]  = {above+s0, above+s1, above+s2, above+s3};
            unsigned int sufN[4] = {above+s1, above+s2, above+s3, above};
#pragma unroll
            for (int k2 = 0; k2 < 4; ++k2)
                if (suf[k2] >= need && sufN[k2] < need) {
                    s_bin = (unsigned int)(lane*4 + k2); s_above = sufN[k2];
                }
        }
        __syncthreads();
        pref |= s_bin << shift;
        need -= s_above;
        __syncthreads();
    }
    unsigned int T = pref;   // exact threshold key; `need` = #equals to take
    unsigned int eq = 0;
#pragma unroll
    for (int j = 0; j < 6; ++j) eq += (keys[tid * 6 + j] == T) ? 1u : 0u;
    hist[tid] = eq;
    __syncthreads();
    if (tid < 64) {
        int lane = tid;
        unsigned int e0 = hist[lane*4+0], e1 = hist[lane*4+1];
        unsigned int e2 = hist[lane*4+2], e3 = hist[lane*4+3];
        unsigned int tot = e0 + e1 + e2 + e3;
        unsigned int run = tot;
#pragma unroll
        for (int off = 1; off < 64; off <<= 1) {
            unsigned int v = __shfl_up(run, off);
            if (lane >= off) run += v;
        }
        unsigned int base = run - tot;  // exclusive prefix over lane totals
        hist[lane*4+0] = base;
        hist[lane*4+1] = base + e0;
        hist[lane*4+2] = base + e0 + e1;
        hist[lane*4+3] = base + e0 + e1 + e2;
    }
    __syncthreads();
    unsigned int myBase = hist[tid];
    int outBase = ((p * kV + q) * kN + n) * kTopK;
    unsigned int eqSeen = 0;
#pragma unroll
    for (int j = 0; j < 6; ++j) {
        int i = tid * 6 + j;
        unsigned int k = keys[i];
        bool take = (k > T);
        if (k == T) { take = (myBase + eqSeen < need); eqSeen++; }
        if (take && k > 0x80000000u) {      // value > 0 filter
            unsigned int pos = atomicAdd(&s_cnt, 1u);
            idxOut[outBase + pos] = i;
        }
    }
    __syncthreads();
    if (tid == 0) cntOut[(p * kV + q) * kN + n] = (int)s_cnt;
}

// ---- scores + per-(p,q) softmax + V gather + final fuse ------------------
// Scores: 192 threads = 2 per row (halves of D), wave g == q-group g.
// Gather: 4 waves x 24 rows, lane covers 4 dims, branch-free, LDS reduce.
__global__ __launch_bounds__(256) void fuse_kernel(
    const __bf16* __restrict__ Qn, const __bf16* __restrict__ Kn,
    const __bf16* __restrict__ Vn, const float* __restrict__ Vmean,
    const int* __restrict__ idxBuf, const int* __restrict__ cntBuf,
    const float* __restrict__ alignedF, const float* __restrict__ H,
    const float* __restrict__ alpha_align, const float* __restrict__ beta,
    float* __restrict__ out)
{
    int n = blockIdx.x, p = blockIdx.y, tid = threadIdx.x;
    __shared__ float qsh[kD];
    __shared__ float wsh[96];
    __shared__ int   osh[96];
    __shared__ float part[4][kD];
    qsh[tid] = (float)Qn[((size_t)p * kN + n) * kD + tid];
    __syncthreads();
    if (tid < 192) {
        int j = tid >> 1, half = tid & 1;
        int g = j >> 5, r = j & 31;
        int q = g + (g >= p ? 1 : 0);
        int cnt = cntBuf[(p * kV + q) * kN + n];
        bool valid = (r < cnt);
        int m = valid ? idxBuf[((p * kV + q) * kN + n) * kTopK + r] : 0;
        int off = valid ? (q * kN + m) * kD : 0;
        float s = 0.f;
        if (valid) {
            const __bf16* kr = Kn + off + half * 128;
            const float*  qh = qsh + half * 128;
            float a0 = 0.f, a1 = 0.f, a2 = 0.f, a3 = 0.f;
#pragma unroll
            for (int dd = 0; dd < 128; dd += 32) {
                bf16x8 k0 = *(const bf16x8*)(kr + dd);
                bf16x8 k1 = *(const bf16x8*)(kr + dd + 8);
                bf16x8 k2 = *(const bf16x8*)(kr + dd + 16);
                bf16x8 k3 = *(const bf16x8*)(kr + dd + 24);
                const float* q0 = qh + dd;
#pragma unroll
                for (int e = 0; e < 8; ++e) {
                    a0 += q0[e]      * (float)k0[e];
                    a1 += q0[e + 8]  * (float)k1[e];
                    a2 += q0[e + 16] * (float)k2[e];
                    a3 += q0[e + 24] * (float)k3[e];
                }
            }
            s = (a0 + a1) + (a2 + a3);
        }
        s += __shfl_xor(s, 1);
        float sc = valid ? s * 0.0625f : -1e30f;   // 1/sqrt(256)
        float mx = sc;
#pragma unroll
        for (int o2 = 2; o2 <= 32; o2 <<= 1) mx = fmaxf(mx, __shfl_xor(mx, o2));
        float e = valid ? __expf(sc - mx) : 0.f;
        float ss = e;
#pragma unroll
        for (int o2 = 2; o2 <= 32; o2 <<= 1) ss += __shfl_xor(ss, o2);
        if (half == 0) {
            wsh[j] = (ss > 0.f) ? e / ss : 0.f;
            osh[j] = off;
        }
    }
    __syncthreads();
    {
        int wv = tid >> 6, lane = tid & 63;
        float a0 = 0.f, a1 = 0.f, a2 = 0.f, a3 = 0.f;
#pragma unroll
        for (int jj = 0; jj < 24; ++jj) {
            int j = wv * 24 + jj;
            float w_ = wsh[j];
            bf16x4 v = *(const bf16x4*)(Vn + osh[j] + lane * 4);
            a0 += w_ * (float)v[0]; a1 += w_ * (float)v[1];
            a2 += w_ * (float)v[2]; a3 += w_ * (float)v[3];
        }
        part[wv][lane * 4 + 0] = a0; part[wv][lane * 4 + 1] = a1;
        part[wv][lane * 4 + 2] = a2; part[wv][lane * 4 + 3] = a3;
    }
    __syncthreads();
    float acc = Vmean[p * kD + tid]
              + part[0][tid] + part[1][tid] + part[2][tid] + part[3][tid];
    float aa = 1.f / (1.f + __expf(-alpha_align[0]));
    float bt = beta[0];
    size_t off = ((size_t)p * kN + n) * kD + tid;
    float al = alignedF[off];
    float f  = fmaxf(aa * al + (1.f - aa) * acc, 0.f);
    out[off] = H[off] * bt + (1.f - bt) * f;
}

extern "C" void kernel_launch(void* const* d_in, const int* in_sizes, int n_in,
                              void* d_out, int out_size, void* d_ws, size_t ws_size,
                              hipStream_t stream)
{
    const float* H        = (const float*)d_in[0];
    const float* C        = (const float*)d_in[1];
    const float* WQ       = (const float*)d_in[2];
    const float* WK       = (const float*)d_in[3];
    const float* WV       = (const float*)d_in[4];
    const float* inW      = (const float*)d_in[5];
    const float* inB      = (const float*)d_in[6];
    const float* outW     = (const float*)d_in[7];
    const float* outBias  = (const float*)d_in[8];
    const float* alphas   = (const float*)d_in[9];
    const float* alpha_al = (const float*)d_in[10];
    const float* beta     = (const float*)d_in[11];
    float* out = (float*)d_out;

    char* w = (char*)d_ws;
    __bf16* qkv      = (__bf16*)w;  w += (size_t)6144 * 768 * 2;   // 9.4 MB
    float*  o        = (float*)w;   w += (size_t)6144 * 256 * 4;   // 6.3 MB
    float*  alignedF = (float*)w;   w += (size_t)6144 * 256 * 4;   // 6.3 MB
    __bf16* Qn       = (__bf16*)w;  w += (size_t)6144 * 256 * 2;   // 3.1 MB
    __bf16* Kn       = (__bf16*)w;  w += (size_t)6144 * 256 * 2;
    __bf16* Vn       = (__bf16*)w;  w += (size_t)6144 * 256 * 2;
    float*  Vmean    = (float*)w;   w += (size_t)4 * 256 * 4;
    int*    idxBuf   = (int*)w;     w += (size_t)16 * 1536 * 32 * 4; // 3.1 MB
    int*    cntBuf   = (int*)w;                                      // 0.1 MB

    // 1) qkv = H @ inW^T + inB (6144 x 768 x 256) -> bf16
    gemm_bt_kernel<<<1152, 256, 0, stream>>>(H, inW, inB, 6144, 768, 256,
        0, qkv, nullptr, nullptr, nullptr, 0);
    // 2) 4x4 attention per (n,h) -> o (f32)
    attn_kernel<<<1536, 256, 0, stream>>>(qkv, o);
    // 3) aligned = alphas*(o @ outW^T + b) + (1-alphas)*H -> f32
    gemm_bt_kernel<<<384, 256, 0, stream>>>(o, outW, outBias, 6144, 256, 256,
        1, nullptr, alignedF, H, alphas, 1536);
    // 4) stage-2 projections (per-view weights), single launch -> bf16
    gemm_qkv3_kernel<<<dim3(384, 3), 256, 0, stream>>>(alignedF, WQ, WK, WV, Qn, Kn, Vn);
    // 5) Vmean (q==p uniform softmax term)
    vmean_kernel<<<4, 1024, 0, stream>>>(Vn, Vmean);
    // 6) top-32 of each C row, p != q only (radix select)
    topk_kernel<<<dim3(1536, 12), 256, 0, stream>>>(C, idxBuf, cntBuf);
    // 7) scores + softmax + gather + fuse -> out
    fuse_kernel<<<dim3(1536, 4), 256, 0, stream>>>(Qn, Kn, Vn, Vmean, idxBuf, cntBuf,
        alignedF, H, alpha_al, beta, out);
}

// Round 5
// 408.552 us; speedup vs baseline: 2.5658x; 1.1948x over previous
//
#include <hip/hip_runtime.h>
#include <hip/hip_bf16.h>
#include <math.h>

typedef __bf16 bf16x8 __attribute__((ext_vector_type(8)));
typedef __bf16 bf16x4 __attribute__((ext_vector_type(4)));
typedef float  f32x4  __attribute__((ext_vector_type(4)));

static constexpr int kV = 4;
static constexpr int kN = 1536;
static constexpr int kD = 256;
static constexpr int kTopK = 32;

// ---- one-shot f32 -> bf16 pre-convert of H + all weights ------------------
__global__ __launch_bounds__(256) void convert_kernel(
    const float* __restrict__ H, const float* __restrict__ inW,
    const float* __restrict__ outW, const float* __restrict__ WQ,
    const float* __restrict__ WK, const float* __restrict__ WV,
    __bf16* __restrict__ Hb, __bf16* __restrict__ inWb,
    __bf16* __restrict__ outWb, __bf16* __restrict__ Wqkvb)
{
    int idx = (blockIdx.x * 256 + threadIdx.x) * 4;
    const float* src; __bf16* dst; int off;
    if      (idx < 1572864) { src = H;    dst = Hb;             off = idx; }
    else if (idx < 1769472) { src = inW;  dst = inWb;           off = idx - 1572864; }
    else if (idx < 1835008) { src = outW; dst = outWb;          off = idx - 1769472; }
    else if (idx < 2097152) { src = WQ;   dst = Wqkvb;          off = idx - 1835008; }
    else if (idx < 2359296) { src = WK;   dst = Wqkvb + 262144; off = idx - 2097152; }
    else                    { src = WV;   dst = Wqkvb + 524288; off = idx - 2359296; }
    f32x4 v = *(const f32x4*)(src + off);
    bf16x4 b;
#pragma unroll
    for (int j = 0; j < 4; ++j) b[j] = (__bf16)v[j];
    *(bf16x4*)(dst + off) = b;
}

// ---- GEMM (B^T form, bf16 operands): out[m][n] = sum_k A[m][k]*B[n][k] ----
// Wave tile: (16*MT) x 64. mode 0: bf16 out. mode 1: blend -> f32 + bf16.
template<int MT>
__global__ __launch_bounds__(256) void gemm16(
    const __bf16* __restrict__ A, const __bf16* __restrict__ Bm,
    const float* __restrict__ bias, int Nc, int K, int mode,
    __bf16* __restrict__ outB, float* __restrict__ outF,
    const float* __restrict__ Hres, const float* __restrict__ alphas,
    int rowsPerView)
{
    int wave = blockIdx.x * 4 + (threadIdx.x >> 6);
    int tilesN4 = Nc >> 6;
    int tm  = wave / tilesN4;
    int tn4 = wave - tm * tilesN4;
    int lane = threadIdx.x & 63;
    int r    = lane & 15;
    int quad = lane >> 4;
    const __bf16* Ap = A + (size_t)(tm * 16 * MT + r) * K + quad * 8;
    const __bf16* Bp = Bm + (size_t)(tn4 * 64 + r) * K + quad * 8;
    f32x4 acc[MT][4] = {};
    for (int k0 = 0; k0 < K; k0 += 32) {
        bf16x8 a[MT];
#pragma unroll
        for (int mt = 0; mt < MT; ++mt)
            a[mt] = *(const bf16x8*)(Ap + (size_t)mt * 16 * K + k0);
#pragma unroll
        for (int t = 0; t < 4; ++t) {
            bf16x8 b = *(const bf16x8*)(Bp + (size_t)t * 16 * K + k0);
#pragma unroll
            for (int mt = 0; mt < MT; ++mt)
                acc[mt][t] = __builtin_amdgcn_mfma_f32_16x16x32_bf16(a[mt], b, acc[mt][t], 0, 0, 0);
        }
    }
#pragma unroll
    for (int t = 0; t < 4; ++t) {
        int gn = tn4 * 64 + t * 16 + r;
        float bv = bias ? bias[gn] : 0.f;
#pragma unroll
        for (int mt = 0; mt < MT; ++mt)
#pragma unroll
            for (int i = 0; i < 4; ++i) {
                int gm = tm * 16 * MT + mt * 16 + quad * 4 + i;
                float v = acc[mt][t][i] + bv;
                size_t off = (size_t)gm * Nc + gn;
                if (mode == 0) {
                    outB[off] = (__bf16)v;
                } else {
                    float a_ = alphas[gm / rowsPerView];
                    float res = a_ * v + (1.f - a_) * Hres[off];
                    outF[off] = res;
                    outB[off] = (__bf16)res;
                }
            }
    }
}

// ---- stage-2 Q/K/V projections (per-view W), one launch ------------------
__global__ __launch_bounds__(256) void gemm_qkv3_kernel(
    const __bf16* __restrict__ A, const __bf16* __restrict__ W,
    __bf16* __restrict__ O0, __bf16* __restrict__ O1, __bf16* __restrict__ O2)
{
    __bf16* Ob = (blockIdx.y == 0) ? O0 : (blockIdx.y == 1) ? O1 : O2;
    const __bf16* Wb = W + (size_t)blockIdx.y * 4 * 65536;
    int wave = blockIdx.x * 4 + (threadIdx.x >> 6);
    int tm  = wave >> 2;
    int tn4 = wave & 3;
    int lane = threadIdx.x & 63;
    int r    = lane & 15;
    int quad = lane >> 4;
    const __bf16* Ap = A + (size_t)(tm * 16 + r) * kD + quad * 8;
    const __bf16* Bp = Wb + (size_t)(tm / 96) * 65536 + (size_t)(tn4 * 64 + r) * kD + quad * 8;
    f32x4 acc[4] = {};
    for (int k0 = 0; k0 < kD; k0 += 32) {
        bf16x8 a = *(const bf16x8*)(Ap + k0);
#pragma unroll
        for (int t = 0; t < 4; ++t) {
            bf16x8 b = *(const bf16x8*)(Bp + (size_t)t * 16 * kD + k0);
            acc[t] = __builtin_amdgcn_mfma_f32_16x16x32_bf16(a, b, acc[t], 0, 0, 0);
        }
    }
#pragma unroll
    for (int t = 0; t < 4; ++t) {
        int gn = tn4 * 64 + t * 16 + r;
#pragma unroll
        for (int i = 0; i < 4; ++i) {
            int gm = tm * 16 + quad * 4 + i;
            Ob[(size_t)gm * kD + gn] = (__bf16)acc[t][i];
        }
    }
}

// ---- tiny 4x4 attention per (n,h); wave = one head, lane = d -------------
__global__ __launch_bounds__(256) void attn_kernel(const __bf16* __restrict__ qkv,
                                                   __bf16* __restrict__ o)
{
    int n = blockIdx.x;
    int h = threadIdx.x >> 6;
    int d = threadIdx.x & 63;
    float q[4], k[4], vv[4];
#pragma unroll
    for (int s = 0; s < 4; ++s) {
        size_t base = (size_t)(s * kN + n) * 768 + h * 64 + d;
        q[s]  = (float)qkv[base];
        k[s]  = (float)qkv[base + 256];
        vv[s] = (float)qkv[base + 512];
    }
    float att[4][4];
#pragma unroll
    for (int s = 0; s < 4; ++s)
#pragma unroll
        for (int t = 0; t < 4; ++t) {
            float p = q[s] * k[t];
#pragma unroll
            for (int off = 32; off > 0; off >>= 1) p += __shfl_xor(p, off);
            att[s][t] = p * 0.125f;   // 1/sqrt(64)
        }
#pragma unroll
    for (int s = 0; s < 4; ++s) {
        float mx = fmaxf(fmaxf(att[s][0], att[s][1]), fmaxf(att[s][2], att[s][3]));
        float e0 = __expf(att[s][0] - mx), e1 = __expf(att[s][1] - mx);
        float e2 = __expf(att[s][2] - mx), e3 = __expf(att[s][3] - mx);
        float inv = 1.f / (e0 + e1 + e2 + e3);
        float ov = (e0 * vv[0] + e1 * vv[1] + e2 * vv[2] + e3 * vv[3]) * inv;
        o[(size_t)(s * kN + n) * kD + h * 64 + d] = (__bf16)ov;
    }
}

// ---- Vmean[v][d] += partial over 96 rows (Vmean pre-zeroed) --------------
__global__ __launch_bounds__(256) void vmean_kernel(const __bf16* __restrict__ Vn,
                                                    float* __restrict__ Vmean)
{
    int v = blockIdx.x >> 4, chunk = blockIdx.x & 15;
    int d = threadIdx.x;
    float s = 0.f;
    for (int m = chunk * 96; m < chunk * 96 + 96; ++m)
        s += (float)Vn[((size_t)v * kN + m) * kD + d];
    atomicAdd(&Vmean[v * kD + d], s * (1.f / 1536.f));
}

// ---- exact top-32 per C row (p!=q), radix select, keys in registers ------
__global__ __launch_bounds__(256) void topk_kernel(const float* __restrict__ C,
                                                   int* __restrict__ idxOut,
                                                   int* __restrict__ cntOut)
{
    int n  = blockIdx.x;
    int pi = blockIdx.y;            // 0..11
    int p  = pi / 3;
    int qi = pi % 3;
    int q  = qi + (qi >= p ? 1 : 0);
    int tid = threadIdx.x, wv = tid >> 6, lane = tid & 63;
    __shared__ unsigned int hist4[4][256];
    __shared__ unsigned int hist[256];
    __shared__ unsigned int s_bin, s_above, s_cnt, s_E;
    __shared__ unsigned int wsum[4];
    const float* row = C + ((size_t)((p * kV + q) * kN + n)) * kN;
    unsigned int key[6];
#pragma unroll
    for (int j = 0; j < 6; ++j) {
        unsigned int u = __float_as_uint(row[tid + j * 256]);
        key[j] = (u & 0x80000000u) ? ~u : (u | 0x80000000u);
    }
#pragma unroll
    for (int b = 0; b < 4; ++b) hist4[b][tid] = 0;
    if (tid == 0) s_cnt = 0;
    __syncthreads();
    // pass 0: per-wave histograms on top byte
#pragma unroll
    for (int j = 0; j < 6; ++j) atomicAdd(&hist4[wv][key[j] >> 24], 1u);
    __syncthreads();
    unsigned int pref = 0, need = kTopK;
    if (tid < 64) {
        unsigned int h[4];
#pragma unroll
        for (int k2 = 0; k2 < 4; ++k2)
            h[k2] = hist4[0][lane*4+k2] + hist4[1][lane*4+k2]
                  + hist4[2][lane*4+k2] + hist4[3][lane*4+k2];
        unsigned int s3 = h[3], s2 = h[2] + s3, s1 = h[1] + s2, s0 = h[0] + s1;
        unsigned int run = s0;
#pragma unroll
        for (int off = 1; off < 64; off <<= 1) {
            unsigned int v = __shfl_down(run, off);
            if (lane + off < 64) run += v;
        }
        unsigned int above = run - s0;
        unsigned int suf[4]  = {above+s0, above+s1, above+s2, above+s3};
        unsigned int sufN[4] = {above+s1, above+s2, above+s3, above};
#pragma unroll
        for (int k2 = 0; k2 < 4; ++k2)
            if (suf[k2] >= need && sufN[k2] < need) {
                s_bin = (unsigned int)(lane*4 + k2); s_above = sufN[k2];
            }
    }
    __syncthreads();
    pref |= s_bin << 24;
    need -= s_above;
    __syncthreads();
    // passes 1..3: shared histogram (few matching elements)
    for (int pass = 1; pass < 4; ++pass) {
        const int shift = 24 - 8 * pass;
        hist[tid] = 0;
        __syncthreads();
#pragma unroll
        for (int j = 0; j < 6; ++j)
            if (((key[j] ^ pref) >> (shift + 8)) == 0)
                atomicAdd(&hist[(key[j] >> shift) & 255u], 1u);
        __syncthreads();
        if (tid < 64) {
            unsigned int h0 = hist[lane*4+0], h1 = hist[lane*4+1];
            unsigned int h2 = hist[lane*4+2], h3 = hist[lane*4+3];
            unsigned int s3 = h3, s2 = h2 + s3, s1 = h1 + s2, s0 = h0 + s1;
            unsigned int run = s0;
#pragma unroll
            for (int off = 1; off < 64; off <<= 1) {
                unsigned int v = __shfl_down(run, off);
                if (lane + off < 64) run += v;
            }
            unsigned int above = run - s0;
            unsigned int suf[4]  = {above+s0, above+s1, above+s2, above+s3};
            unsigned int sufN[4] = {above+s1, above+s2, above+s3, above};
#pragma unroll
            for (int k2 = 0; k2 < 4; ++k2)
                if (suf[k2] >= need && sufN[k2] < need) {
                    s_bin = (unsigned int)(lane*4 + k2); s_above = sufN[k2];
                }
        }
        __syncthreads();
        pref |= s_bin << shift;
        need -= s_above;
        __syncthreads();
    }
    unsigned int T = pref;
    // count equals
    unsigned int eq = 0;
#pragma unroll
    for (int j = 0; j < 6; ++j) eq += (key[j] == T) ? 1u : 0u;
    hist[tid] = eq;
    __syncthreads();
    if (tid < 64) {
        unsigned int e = hist[tid] + hist[tid+64] + hist[tid+128] + hist[tid+192];
#pragma unroll
        for (int off = 32; off > 0; off >>= 1) e += __shfl_xor(e, off);
        if (tid == 0) s_E = e;
    }
    __syncthreads();
    unsigned int E = s_E;
    int outBase = ((p * kV + q) * kN + n) * kTopK;
    if (E == need) {
        // fast path (distinct values): take everything >= T that is positive
#pragma unroll
        for (int j = 0; j < 6; ++j) {
            unsigned int k = key[j];
            if (k >= T && k > 0x80000000u) {
                unsigned int pos = atomicAdd(&s_cnt, 1u);
                idxOut[outBase + pos] = tid + j * 256;
            }
        }
    } else {
        // rare: jax tie rule — equals taken in ascending index order
        unsigned int before = 0;
        for (int j = 0; j < 6; ++j) {
            bool e = (key[j] == T);
            unsigned long long m = __ballot(e);
            if (lane == 0) wsum[wv] = (unsigned int)__popcll(m);
            __syncthreads();
            unsigned int base = before;
            for (int w2 = 0; w2 < 4; ++w2) if (w2 < wv) base += wsum[w2];
            unsigned int rank = base + (unsigned int)__popcll(m & ((1ull << lane) - 1ull));
            unsigned int k = key[j];
            bool take = (k > T) || (e && rank < need);
            if (take && k > 0x80000000u) {
                unsigned int pos = atomicAdd(&s_cnt, 1u);
                idxOut[outBase + pos] = tid + j * 256;
            }
            before += wsum[0] + wsum[1] + wsum[2] + wsum[3];
            __syncthreads();
        }
    }
    __syncthreads();
    if (tid == 0) cntOut[(p * kV + q) * kN + n] = (int)s_cnt;
}

// ---- scores + per-(p,q) softmax + V gather + final fuse ------------------
__global__ __launch_bounds__(256) void fuse_kernel(
    const __bf16* __restrict__ Qn, const __bf16* __restrict__ Kn,
    const __bf16* __restrict__ Vn, const float* __restrict__ Vmean,
    const int* __restrict__ idxBuf, const int* __restrict__ cntBuf,
    const float* __restrict__ alignedF, const float* __restrict__ H,
    const float* __restrict__ alpha_align, const float* __restrict__ beta,
    float* __restrict__ out)
{
    int n = blockIdx.x, p = blockIdx.y, tid = threadIdx.x;
    __shared__ float qsh[kD];
    __shared__ float wsh[96];
    __shared__ int   osh[96];
    __shared__ float part[4][kD];
    qsh[tid] = (float)Qn[((size_t)p * kN + n) * kD + tid];
    __syncthreads();
    if (tid < 192) {
        int j = tid >> 1, half = tid & 1;
        int g = j >> 5, r = j & 31;
        int q = g + (g >= p ? 1 : 0);
        int cnt = cntBuf[(p * kV + q) * kN + n];
        bool valid = (r < cnt);
        int m = valid ? idxBuf[((p * kV + q) * kN + n) * kTopK + r] : 0;
        int off = valid ? (q * kN + m) * kD : 0;
        float s = 0.f;
        if (valid) {
            const __bf16* kr = Kn + off + half * 128;
            const float*  qh = qsh + half * 128;
            float a0 = 0.f, a1 = 0.f, a2 = 0.f, a3 = 0.f;
#pragma unroll
            for (int dd = 0; dd < 128; dd += 32) {
                bf16x8 k0 = *(const bf16x8*)(kr + dd);
                bf16x8 k1 = *(const bf16x8*)(kr + dd + 8);
                bf16x8 k2 = *(const bf16x8*)(kr + dd + 16);
                bf16x8 k3 = *(const bf16x8*)(kr + dd + 24);
                const float* q0 = qh + dd;
#pragma unroll
                for (int e = 0; e < 8; ++e) {
                    a0 += q0[e]      * (float)k0[e];
                    a1 += q0[e + 8]  * (float)k1[e];
                    a2 += q0[e + 16] * (float)k2[e];
                    a3 += q0[e + 24] * (float)k3[e];
                }
            }
            s = (a0 + a1) + (a2 + a3);
        }
        s += __shfl_xor(s, 1);
        float sc = valid ? s * 0.0625f : -1e30f;   // 1/sqrt(256)
        float mx = sc;
#pragma unroll
        for (int o2 = 2; o2 <= 32; o2 <<= 1) mx = fmaxf(mx, __shfl_xor(mx, o2));
        float e = valid ? __expf(sc - mx) : 0.f;
        float ss = e;
#pragma unroll
        for (int o2 = 2; o2 <= 32; o2 <<= 1) ss += __shfl_xor(ss, o2);
        if (half == 0) {
            wsh[j] = (ss > 0.f) ? e / ss : 0.f;
            osh[j] = off;
        }
    }
    __syncthreads();
    {
        int wv = tid >> 6, lane = tid & 63;
        float a0 = 0.f, a1 = 0.f, a2 = 0.f, a3 = 0.f;
#pragma unroll
        for (int jj = 0; jj < 24; ++jj) {
            int j = wv * 24 + jj;
            float w_ = wsh[j];
            bf16x4 v = *(const bf16x4*)(Vn + osh[j] + lane * 4);
            a0 += w_ * (float)v[0]; a1 += w_ * (float)v[1];
            a2 += w_ * (float)v[2]; a3 += w_ * (float)v[3];
        }
        part[wv][lane * 4 + 0] = a0; part[wv][lane * 4 + 1] = a1;
        part[wv][lane * 4 + 2] = a2; part[wv][lane * 4 + 3] = a3;
    }
    __syncthreads();
    float acc = Vmean[p * kD + tid]
              + part[0][tid] + part[1][tid] + part[2][tid] + part[3][tid];
    float aa = 1.f / (1.f + __expf(-alpha_align[0]));
    float bt = beta[0];
    size_t off = ((size_t)p * kN + n) * kD + tid;
    float al = alignedF[off];
    float f  = fmaxf(aa * al + (1.f - aa) * acc, 0.f);
    out[off] = H[off] * bt + (1.f - bt) * f;
}

extern "C" void kernel_launch(void* const* d_in, const int* in_sizes, int n_in,
                              void* d_out, int out_size, void* d_ws, size_t ws_size,
                              hipStream_t stream)
{
    const float* H        = (const float*)d_in[0];
    const float* C        = (const float*)d_in[1];
    const float* WQ       = (const float*)d_in[2];
    const float* WK       = (const float*)d_in[3];
    const float* WV       = (const float*)d_in[4];
    const float* inW      = (const float*)d_in[5];
    const float* inB      = (const float*)d_in[6];
    const float* outW     = (const float*)d_in[7];
    const float* outBias  = (const float*)d_in[8];
    const float* alphas   = (const float*)d_in[9];
    const float* alpha_al = (const float*)d_in[10];
    const float* beta     = (const float*)d_in[11];
    float* out = (float*)d_out;

    char* w = (char*)d_ws;
    __bf16* Hb       = (__bf16*)w;  w += (size_t)6144 * 256 * 2;
    __bf16* inWb     = (__bf16*)w;  w += (size_t)768 * 256 * 2;
    __bf16* outWb    = (__bf16*)w;  w += (size_t)256 * 256 * 2;
    __bf16* Wqkvb    = (__bf16*)w;  w += (size_t)3 * 4 * 256 * 256 * 2;
    __bf16* qkv      = (__bf16*)w;  w += (size_t)6144 * 768 * 2;
    __bf16* ob       = (__bf16*)w;  w += (size_t)6144 * 256 * 2;
    __bf16* alignedB = (__bf16*)w;  w += (size_t)6144 * 256 * 2;
    float*  alignedF = (float*)w;   w += (size_t)6144 * 256 * 4;
    __bf16* Qn       = (__bf16*)w;  w += (size_t)6144 * 256 * 2;
    __bf16* Kn       = (__bf16*)w;  w += (size_t)6144 * 256 * 2;
    __bf16* Vn       = (__bf16*)w;  w += (size_t)6144 * 256 * 2;
    float*  Vmean    = (float*)w;   w += (size_t)4 * 256 * 4;
    int*    idxBuf   = (int*)w;     w += (size_t)16 * 1536 * 32 * 4;
    int*    cntBuf   = (int*)w;

    // 0) pre-convert inputs to bf16; zero Vmean accumulator
    hipMemsetAsync(Vmean, 0, 4 * 256 * 4, stream);
    convert_kernel<<<2560, 256, 0, stream>>>(H, inW, outW, WQ, WK, WV,
                                             Hb, inWb, outWb, Wqkvb);
    // 1) qkv = H @ inW^T + inB (6144 x 768 x 256), 32x64 wave tile
    gemm16<2><<<576, 256, 0, stream>>>(Hb, inWb, inB, 768, 256,
        0, qkv, nullptr, nullptr, nullptr, 0);
    // 2) 4x4 attention per (n,h) -> o (bf16)
    attn_kernel<<<1536, 256, 0, stream>>>(qkv, ob);
    // 3) aligned = alphas*(o @ outW^T + b) + (1-alphas)*H -> f32 + bf16
    gemm16<1><<<384, 256, 0, stream>>>(ob, outWb, outBias, 256, 256,
        1, alignedB, alignedF, H, alphas, 1536);
    // 4) stage-2 projections (per-view weights), single launch -> bf16
    gemm_qkv3_kernel<<<dim3(384, 3), 256, 0, stream>>>(alignedB, Wqkvb, Qn, Kn, Vn);
    // 5) Vmean (q==p uniform softmax term)
    vmean_kernel<<<64, 256, 0, stream>>>(Vn, Vmean);
    // 6) top-32 of each C row, p != q only (register radix select)
    topk_kernel<<<dim3(1536, 12), 256, 0, stream>>>(C, idxBuf, cntBuf);
    // 7) scores + softmax + gather + fuse -> out
    fuse_kernel<<<dim3(1536, 4), 256, 0, stream>>>(Qn, Kn, Vn, Vmean, idxBuf, cntBuf,
        alignedF, H, alpha_al, beta, out);
}

// Round 6
// 377.691 us; speedup vs baseline: 2.7755x; 1.0817x over previous
//
#include <hip/hip_runtime.h>
#include <hip/hip_bf16.h>
#include <math.h>

typedef __bf16 bf16x8 __attribute__((ext_vector_type(8)));
typedef __bf16 bf16x4 __attribute__((ext_vector_type(4)));
typedef float  f32x4  __attribute__((ext_vector_type(4)));

static constexpr int kV = 4;
static constexpr int kN = 1536;
static constexpr int kD = 256;
static constexpr int kTopK = 32;

// ---- f32 -> bf16 pre-convert of H + all weights; also zeros Vmean --------
__global__ __launch_bounds__(256) void convert_kernel(
    const float* __restrict__ H, const float* __restrict__ inW,
    const float* __restrict__ outW, const float* __restrict__ WQ,
    const float* __restrict__ WK, const float* __restrict__ WV,
    __bf16* __restrict__ Hb, __bf16* __restrict__ inWb,
    __bf16* __restrict__ outWb, __bf16* __restrict__ Wqkvb,
    float* __restrict__ Vmean)
{
    if (blockIdx.x == 0) {
        f32x4 z = {0.f, 0.f, 0.f, 0.f};
        *(f32x4*)(Vmean + threadIdx.x * 4) = z;   // 256*4 = 1024 floats
    }
    int idx = (blockIdx.x * 256 + threadIdx.x) * 4;
    const float* src; __bf16* dst; int off;
    if      (idx < 1572864) { src = H;    dst = Hb;             off = idx; }
    else if (idx < 1769472) { src = inW;  dst = inWb;           off = idx - 1572864; }
    else if (idx < 1835008) { src = outW; dst = outWb;          off = idx - 1769472; }
    else if (idx < 2097152) { src = WQ;   dst = Wqkvb;          off = idx - 1835008; }
    else if (idx < 2359296) { src = WK;   dst = Wqkvb + 262144; off = idx - 2097152; }
    else                    { src = WV;   dst = Wqkvb + 524288; off = idx - 2359296; }
    f32x4 v = *(const f32x4*)(src + off);
    bf16x4 b;
#pragma unroll
    for (int j = 0; j < 4; ++j) b[j] = (__bf16)v[j];
    *(bf16x4*)(dst + off) = b;
}

// ---- qkv = Hb @ inWb^T + (bias later in attn? no: bias added here) -------
// Wave tile 32x64. out bf16 (bias folded in f32 before cvt).
__global__ __launch_bounds__(256) void gemm_qkv_kernel(
    const __bf16* __restrict__ A, const __bf16* __restrict__ Bm,
    const float* __restrict__ bias, __bf16* __restrict__ outB)
{
    const int Nc = 768, K = 256;
    int wave = blockIdx.x * 4 + (threadIdx.x >> 6);
    int tm  = wave / 12;
    int tn4 = wave - tm * 12;
    int lane = threadIdx.x & 63;
    int r    = lane & 15;
    int quad = lane >> 4;
    const __bf16* Ap = A + (size_t)(tm * 32 + r) * K + quad * 8;
    const __bf16* Bp = Bm + (size_t)(tn4 * 64 + r) * K + quad * 8;
    f32x4 acc[2][4] = {};
    for (int k0 = 0; k0 < K; k0 += 32) {
        bf16x8 a0 = *(const bf16x8*)(Ap + k0);
        bf16x8 a1 = *(const bf16x8*)(Ap + (size_t)16 * K + k0);
#pragma unroll
        for (int t = 0; t < 4; ++t) {
            bf16x8 b = *(const bf16x8*)(Bp + (size_t)t * 16 * K + k0);
            acc[0][t] = __builtin_amdgcn_mfma_f32_16x16x32_bf16(a0, b, acc[0][t], 0, 0, 0);
            acc[1][t] = __builtin_amdgcn_mfma_f32_16x16x32_bf16(a1, b, acc[1][t], 0, 0, 0);
        }
    }
#pragma unroll
    for (int t = 0; t < 4; ++t) {
        int gn = tn4 * 64 + t * 16 + r;
        float bv = bias[gn];
#pragma unroll
        for (int mt = 0; mt < 2; ++mt)
#pragma unroll
            for (int i = 0; i < 4; ++i) {
                int gm = tm * 32 + mt * 16 + quad * 4 + i;
                outB[(size_t)gm * Nc + gn] = (__bf16)(acc[mt][t][i] + bv);
            }
    }
}

// ---- attn (4x4 per n,h) + out-proj GEMM + alpha-blend, fused -------------
// Block: 4 n values x 4 views = 16 rows; o kept in LDS.
__global__ __launch_bounds__(256) void attg3_kernel(
    const __bf16* __restrict__ qkv, const __bf16* __restrict__ outWb,
    const float* __restrict__ outBias, const float* __restrict__ H,
    const float* __restrict__ alphas,
    float* __restrict__ alignedF, __bf16* __restrict__ alignedB)
{
    __shared__ __bf16 obuf[16][280];   // row = s*4+ni, padded to 280 (560 B)
    int n0 = blockIdx.x * 4;
    int tid = threadIdx.x;
    int h = tid >> 6, d = tid & 63;
#pragma unroll
    for (int ni = 0; ni < 4; ++ni) {
        int n = n0 + ni;
        float q[4], k[4], vv[4];
#pragma unroll
        for (int s = 0; s < 4; ++s) {
            size_t base = (size_t)(s * kN + n) * 768 + h * 64 + d;
            q[s]  = (float)qkv[base];
            k[s]  = (float)qkv[base + 256];
            vv[s] = (float)qkv[base + 512];
        }
        float att[4][4];
#pragma unroll
        for (int s = 0; s < 4; ++s)
#pragma unroll
            for (int t = 0; t < 4; ++t) {
                float p = q[s] * k[t];
#pragma unroll
                for (int off = 32; off > 0; off >>= 1) p += __shfl_xor(p, off);
                att[s][t] = p * 0.125f;   // 1/sqrt(64)
            }
#pragma unroll
        for (int s = 0; s < 4; ++s) {
            float mx = fmaxf(fmaxf(att[s][0], att[s][1]), fmaxf(att[s][2], att[s][3]));
            float e0 = __expf(att[s][0] - mx), e1 = __expf(att[s][1] - mx);
            float e2 = __expf(att[s][2] - mx), e3 = __expf(att[s][3] - mx);
            float inv = 1.f / (e0 + e1 + e2 + e3);
            float ov = (e0 * vv[0] + e1 * vv[1] + e2 * vv[2] + e3 * vv[3]) * inv;
            obuf[s * 4 + ni][h * 64 + d] = (__bf16)ov;
        }
    }
    __syncthreads();
    // gemm3: A = obuf (16 x 256), B = outWb^T; wave w covers cols w*64..+63
    int w = tid >> 6, lane = tid & 63;
    int r = lane & 15, quad = lane >> 4;
    f32x4 acc[4] = {};
    for (int k0 = 0; k0 < 256; k0 += 32) {
        bf16x8 a = *(const bf16x8*)&obuf[r][quad * 8 + k0];
#pragma unroll
        for (int t = 0; t < 4; ++t) {
            bf16x8 b = *(const bf16x8*)(outWb + (size_t)(w * 64 + t * 16 + r) * 256 + quad * 8 + k0);
            acc[t] = __builtin_amdgcn_mfma_f32_16x16x32_bf16(a, b, acc[t], 0, 0, 0);
        }
    }
#pragma unroll
    for (int t = 0; t < 4; ++t) {
        int gn = w * 64 + t * 16 + r;
        float bv = outBias[gn];
#pragma unroll
        for (int i = 0; i < 4; ++i) {
            int rl = quad * 4 + i;          // C/D row in tile = s*4+ni
            int s = rl >> 2, ni = rl & 3;
            size_t gr = (size_t)(s * kN + n0 + ni);
            float a_ = alphas[s];
            size_t off = gr * kD + gn;
            float res = a_ * (acc[t][i] + bv) + (1.f - a_) * H[off];
            alignedF[off] = res;
            alignedB[off] = (__bf16)res;
        }
    }
}

// ---- stage-2 Q/K/V projections (per-view W) + fused Vmean ----------------
// Grid (192, 3): y = projection; block covers 32 rows x 256 cols, MT=2.
__global__ __launch_bounds__(256) void gemm_qkv3_kernel(
    const __bf16* __restrict__ A, const __bf16* __restrict__ W,
    __bf16* __restrict__ O0, __bf16* __restrict__ O1, __bf16* __restrict__ O2,
    float* __restrict__ Vmean)
{
    int proj = blockIdx.y;
    __bf16* Ob = (proj == 0) ? O0 : (proj == 1) ? O1 : O2;
    const __bf16* Wb = W + (size_t)proj * 4 * 65536;
    int b = blockIdx.x;                 // 32-row group
    int view = b / 48;
    int tn4 = threadIdx.x >> 6;         // wave = col group
    int lane = threadIdx.x & 63;
    int r = lane & 15, quad = lane >> 4;
    const __bf16* Ap = A + (size_t)(b * 32 + r) * kD + quad * 8;
    const __bf16* Bp = Wb + (size_t)view * 65536 + (size_t)(tn4 * 64 + r) * kD + quad * 8;
    f32x4 acc[2][4] = {};
    for (int k0 = 0; k0 < kD; k0 += 32) {
        bf16x8 a0 = *(const bf16x8*)(Ap + k0);
        bf16x8 a1 = *(const bf16x8*)(Ap + (size_t)16 * kD + k0);
#pragma unroll
        for (int t = 0; t < 4; ++t) {
            bf16x8 bb = *(const bf16x8*)(Bp + (size_t)t * 16 * kD + k0);
            acc[0][t] = __builtin_amdgcn_mfma_f32_16x16x32_bf16(a0, bb, acc[0][t], 0, 0, 0);
            acc[1][t] = __builtin_amdgcn_mfma_f32_16x16x32_bf16(a1, bb, acc[1][t], 0, 0, 0);
        }
    }
#pragma unroll
    for (int t = 0; t < 4; ++t) {
        int gn = tn4 * 64 + t * 16 + r;
#pragma unroll
        for (int mt = 0; mt < 2; ++mt)
#pragma unroll
            for (int i = 0; i < 4; ++i) {
                int gm = b * 32 + mt * 16 + quad * 4 + i;
                Ob[(size_t)gm * kD + gn] = (__bf16)acc[mt][t][i];
            }
    }
    if (proj == 2) {   // Vmean partial: sum this block's 32 rows per column
#pragma unroll
        for (int t = 0; t < 4; ++t) {
            float cs = 0.f;
#pragma unroll
            for (int mt = 0; mt < 2; ++mt)
#pragma unroll
                for (int i = 0; i < 4; ++i) cs += acc[mt][t][i];
            cs += __shfl_xor(cs, 16);
            cs += __shfl_xor(cs, 32);
            if (quad == 0)
                atomicAdd(&Vmean[view * kD + tn4 * 64 + t * 16 + r], cs * (1.f / 1536.f));
        }
    }
}

// ---- crcva: topk (wave-per-row, barrier-free) + scores + gather + fuse ---
__global__ __launch_bounds__(256) void crcva_kernel(
    const float* __restrict__ C,
    const __bf16* __restrict__ Qn, const __bf16* __restrict__ Kn,
    const __bf16* __restrict__ Vn, const float* __restrict__ Vmean,
    const float* __restrict__ alignedF, const float* __restrict__ H,
    const float* __restrict__ alpha_align, const float* __restrict__ beta,
    float* __restrict__ out)
{
    int n = blockIdx.x, p = blockIdx.y, tid = threadIdx.x;
    int w = tid >> 6, lane = tid & 63;
    __shared__ unsigned int hist[3][256];
    __shared__ unsigned int idxl[3][kTopK];
    __shared__ unsigned int scnt[3];
    __shared__ float qsh[kD];
    __shared__ float wsh[96];
    __shared__ int   osh[96];
    __shared__ float part[4][kD];

    if (w < 3) {
        // ---- wave-local exact top-32 radix select on row (p, q, n) ----
        int q = w + (w >= p ? 1 : 0);
        const float* row = C + ((size_t)((p * kV + q) * kN + n)) * kN;
        unsigned int key[24];
#pragma unroll
        for (int j = 0; j < 24; ++j) {
            unsigned int u = __float_as_uint(row[j * 64 + lane]);
            key[j] = (u & 0x80000000u) ? ~u : (u | 0x80000000u);
        }
        if (lane == 0) scnt[w] = 0;
        unsigned int pref = 0, need = kTopK;
#pragma unroll
        for (int pass = 0; pass < 4; ++pass) {
            const int shift = 24 - 8 * pass;
#pragma unroll
            for (int k2 = 0; k2 < 4; ++k2) hist[w][lane + k2 * 64] = 0;
            __builtin_amdgcn_wave_barrier();
#pragma unroll
            for (int j = 0; j < 24; ++j) {
                unsigned int k = key[j];
                bool match = (pass == 0) || (((k ^ pref) >> (shift + 8)) == 0);
                if (match) atomicAdd(&hist[w][(k >> shift) & 255u], 1u);
            }
            __builtin_amdgcn_wave_barrier();
            unsigned int h0 = hist[w][lane*4+0], h1 = hist[w][lane*4+1];
            unsigned int h2 = hist[w][lane*4+2], h3 = hist[w][lane*4+3];
            unsigned int s3 = h3, s2 = h2 + s3, s1 = h1 + s2, s0 = h0 + s1;
            unsigned int run = s0;
#pragma unroll
            for (int off = 1; off < 64; off <<= 1) {
                unsigned int v = __shfl_down(run, off);
                if (lane + off < 64) run += v;
            }
            unsigned int above = run - s0;
            unsigned int suf[4]  = {above+s0, above+s1, above+s2, above+s3};
            unsigned int sufN[4] = {above+s1, above+s2, above+s3, above};
            unsigned int pk = 0;
#pragma unroll
            for (int k2 = 0; k2 < 4; ++k2)
                if (suf[k2] >= need && sufN[k2] < need)
                    pk = ((unsigned int)(lane*4 + k2) << 16) | sufN[k2];
#pragma unroll
            for (int off = 1; off < 64; off <<= 1) pk |= __shfl_xor(pk, off);
            pref |= (pk >> 16) << shift;
            need -= (pk & 0xffffu);
        }
        unsigned int T = pref;
        unsigned int eqBefore = 0;
#pragma unroll
        for (int j = 0; j < 24; ++j) {
            unsigned int k = key[j];
            bool e = (k == T);
            unsigned long long m = __ballot(e);
            unsigned int rank = eqBefore + (unsigned int)__popcll(m & ((1ull << lane) - 1ull));
            bool take = (k > T) || (e && rank < need);
            if (take && k > 0x80000000u) {
                unsigned int pos = atomicAdd(&scnt[w], 1u);
                idxl[w][pos] = (unsigned int)(j * 64 + lane);
            }
            eqBefore += (unsigned int)__popcll(m);
        }
    } else {
        // wave 3: stage Qn row into LDS as f32
        bf16x4 qv = *(const bf16x4*)(Qn + ((size_t)p * kN + n) * kD + lane * 4);
#pragma unroll
        for (int e = 0; e < 4; ++e) qsh[lane * 4 + e] = (float)qv[e];
    }
    __syncthreads();

    // ---- scores + per-(p,q) softmax (2 threads per candidate row) ----
    if (tid < 192) {
        int j = tid >> 1, half = tid & 1;
        int g = j >> 5, r = j & 31;
        int q = g + (g >= p ? 1 : 0);
        int cnt = (int)scnt[g];
        bool valid = (r < cnt);
        int m = valid ? (int)idxl[g][r] : 0;
        int off = valid ? (q * kN + m) * kD : 0;
        float s = 0.f;
        if (valid) {
            const __bf16* kr = Kn + off + half * 128;
            const float*  qh = qsh + half * 128;
            float a0 = 0.f, a1 = 0.f, a2 = 0.f, a3 = 0.f;
#pragma unroll
            for (int dd = 0; dd < 128; dd += 32) {
                bf16x8 k0 = *(const bf16x8*)(kr + dd);
                bf16x8 k1 = *(const bf16x8*)(kr + dd + 8);
                bf16x8 k2 = *(const bf16x8*)(kr + dd + 16);
                bf16x8 k3 = *(const bf16x8*)(kr + dd + 24);
                const float* q0 = qh + dd;
#pragma unroll
                for (int e = 0; e < 8; ++e) {
                    a0 += q0[e]      * (float)k0[e];
                    a1 += q0[e + 8]  * (float)k1[e];
                    a2 += q0[e + 16] * (float)k2[e];
                    a3 += q0[e + 24] * (float)k3[e];
                }
            }
            s = (a0 + a1) + (a2 + a3);
        }
        s += __shfl_xor(s, 1);
        float sc = valid ? s * 0.0625f : -1e30f;   // 1/sqrt(256)
        float mx = sc;
#pragma unroll
        for (int o2 = 2; o2 <= 32; o2 <<= 1) mx = fmaxf(mx, __shfl_xor(mx, o2));
        float e = valid ? __expf(sc - mx) : 0.f;
        float ss = e;
#pragma unroll
        for (int o2 = 2; o2 <= 32; o2 <<= 1) ss += __shfl_xor(ss, o2);
        if (half == 0) {
            wsh[j] = (ss > 0.f) ? e / ss : 0.f;
            osh[j] = off;
        }
    }
    __syncthreads();

    // ---- weighted V gather: wave w covers 24 rows, 2 rows per iter ----
    {
        int half32 = lane >> 5, l32 = lane & 31;
        float a[8] = {};
#pragma unroll
        for (int it = 0; it < 12; ++it) {
            int j = w * 24 + it * 2 + half32;
            float wt = wsh[j];
            bf16x8 v = *(const bf16x8*)(Vn + osh[j] + l32 * 8);
#pragma unroll
            for (int e = 0; e < 8; ++e) a[e] += wt * (float)v[e];
        }
#pragma unroll
        for (int e = 0; e < 8; ++e) a[e] += __shfl_xor(a[e], 32);
        if (half32 == 0) {
#pragma unroll
            for (int e = 0; e < 8; ++e) part[w][l32 * 8 + e] = a[e];
        }
    }
    __syncthreads();

    float acc = Vmean[p * kD + tid]
              + part[0][tid] + part[1][tid] + part[2][tid] + part[3][tid];
    float aa = 1.f / (1.f + __expf(-alpha_align[0]));
    float bt = beta[0];
    size_t off = ((size_t)p * kN + n) * kD + tid;
    float al = alignedF[off];
    float f  = fmaxf(aa * al + (1.f - aa) * acc, 0.f);
    out[off] = H[off] * bt + (1.f - bt) * f;
}

extern "C" void kernel_launch(void* const* d_in, const int* in_sizes, int n_in,
                              void* d_out, int out_size, void* d_ws, size_t ws_size,
                              hipStream_t stream)
{
    const float* H        = (const float*)d_in[0];
    const float* C        = (const float*)d_in[1];
    const float* WQ       = (const float*)d_in[2];
    const float* WK       = (const float*)d_in[3];
    const float* WV       = (const float*)d_in[4];
    const float* inW      = (const float*)d_in[5];
    const float* inB      = (const float*)d_in[6];
    const float* outW     = (const float*)d_in[7];
    const float* outBias  = (const float*)d_in[8];
    const float* alphas   = (const float*)d_in[9];
    const float* alpha_al = (const float*)d_in[10];
    const float* beta     = (const float*)d_in[11];
    float* out = (float*)d_out;

    char* w = (char*)d_ws;
    __bf16* Hb       = (__bf16*)w;  w += (size_t)6144 * 256 * 2;
    __bf16* inWb     = (__bf16*)w;  w += (size_t)768 * 256 * 2;
    __bf16* outWb    = (__bf16*)w;  w += (size_t)256 * 256 * 2;
    __bf16* Wqkvb    = (__bf16*)w;  w += (size_t)3 * 4 * 256 * 256 * 2;
    __bf16* qkv      = (__bf16*)w;  w += (size_t)6144 * 768 * 2;
    __bf16* alignedB = (__bf16*)w;  w += (size_t)6144 * 256 * 2;
    float*  alignedF = (float*)w;   w += (size_t)6144 * 256 * 4;
    __bf16* Qn       = (__bf16*)w;  w += (size_t)6144 * 256 * 2;
    __bf16* Kn       = (__bf16*)w;  w += (size_t)6144 * 256 * 2;
    __bf16* Vn       = (__bf16*)w;  w += (size_t)6144 * 256 * 2;
    float*  Vmean    = (float*)w;   w += (size_t)4 * 256 * 4;

    // 1) pre-convert + zero Vmean
    convert_kernel<<<2560, 256, 0, stream>>>(H, inW, outW, WQ, WK, WV,
                                             Hb, inWb, outWb, Wqkvb, Vmean);
    // 2) qkv = Hb @ inWb^T + inB
    gemm_qkv_kernel<<<576, 256, 0, stream>>>(Hb, inWb, inB, qkv);
    // 3) attn + out-proj + alpha-blend (o stays in LDS)
    attg3_kernel<<<384, 256, 0, stream>>>(qkv, outWb, outBias, H, alphas,
                                          alignedF, alignedB);
    // 4) Q/K/V projections (per-view W) + fused Vmean
    gemm_qkv3_kernel<<<dim3(192, 3), 256, 0, stream>>>(alignedB, Wqkvb,
                                                       Qn, Kn, Vn, Vmean);
    // 5) topk + scores + softmax + gather + final fuse
    crcva_kernel<<<dim3(1536, 4), 256, 0, stream>>>(C, Qn, Kn, Vn, Vmean,
        alignedF, H, alpha_al, beta, out);
}

// Round 7
// 368.895 us; speedup vs baseline: 2.8416x; 1.0238x over previous
//
#include <hip/hip_runtime.h>
#include <hip/hip_bf16.h>
#include <math.h>

typedef __bf16 bf16x8 __attribute__((ext_vector_type(8)));
typedef __bf16 bf16x4 __attribute__((ext_vector_type(4)));
typedef float  f32x4  __attribute__((ext_vector_type(4)));

static constexpr int kV = 4;
static constexpr int kN = 1536;
static constexpr int kD = 256;
static constexpr int kTopK = 32;

// ---- f32 -> bf16 pre-convert of H + all weights; also zeros Vmean --------
__global__ __launch_bounds__(256) void convert_kernel(
    const float* __restrict__ H, const float* __restrict__ inW,
    const float* __restrict__ outW, const float* __restrict__ WQ,
    const float* __restrict__ WK, const float* __restrict__ WV,
    __bf16* __restrict__ Hb, __bf16* __restrict__ inWb,
    __bf16* __restrict__ outWb, __bf16* __restrict__ Wqkvb,
    float* __restrict__ Vmean)
{
    if (blockIdx.x == 0) {
        f32x4 z = {0.f, 0.f, 0.f, 0.f};
        *(f32x4*)(Vmean + threadIdx.x * 4) = z;   // 256*4 = 1024 floats
    }
    int idx = (blockIdx.x * 256 + threadIdx.x) * 4;
    const float* src; __bf16* dst; int off;
    if      (idx < 1572864) { src = H;    dst = Hb;             off = idx; }
    else if (idx < 1769472) { src = inW;  dst = inWb;           off = idx - 1572864; }
    else if (idx < 1835008) { src = outW; dst = outWb;          off = idx - 1769472; }
    else if (idx < 2097152) { src = WQ;   dst = Wqkvb;          off = idx - 1835008; }
    else if (idx < 2359296) { src = WK;   dst = Wqkvb + 262144; off = idx - 2097152; }
    else                    { src = WV;   dst = Wqkvb + 524288; off = idx - 2359296; }
    f32x4 v = *(const f32x4*)(src + off);
    bf16x4 b;
#pragma unroll
    for (int j = 0; j < 4; ++j) b[j] = (__bf16)v[j];
    *(bf16x4*)(dst + off) = b;
}

// ---- qkv = Hb @ inWb^T + inB; wave tile 32x64 ----------------------------
__global__ __launch_bounds__(256) void gemm_qkv_kernel(
    const __bf16* __restrict__ A, const __bf16* __restrict__ Bm,
    const float* __restrict__ bias, __bf16* __restrict__ outB)
{
    const int Nc = 768, K = 256;
    int wave = blockIdx.x * 4 + (threadIdx.x >> 6);
    int tm  = wave / 12;
    int tn4 = wave - tm * 12;
    int lane = threadIdx.x & 63;
    int r    = lane & 15;
    int quad = lane >> 4;
    const __bf16* Ap = A + (size_t)(tm * 32 + r) * K + quad * 8;
    const __bf16* Bp = Bm + (size_t)(tn4 * 64 + r) * K + quad * 8;
    f32x4 acc[2][4] = {};
    for (int k0 = 0; k0 < K; k0 += 32) {
        bf16x8 a0 = *(const bf16x8*)(Ap + k0);
        bf16x8 a1 = *(const bf16x8*)(Ap + (size_t)16 * K + k0);
#pragma unroll
        for (int t = 0; t < 4; ++t) {
            bf16x8 b = *(const bf16x8*)(Bp + (size_t)t * 16 * K + k0);
            acc[0][t] = __builtin_amdgcn_mfma_f32_16x16x32_bf16(a0, b, acc[0][t], 0, 0, 0);
            acc[1][t] = __builtin_amdgcn_mfma_f32_16x16x32_bf16(a1, b, acc[1][t], 0, 0, 0);
        }
    }
#pragma unroll
    for (int t = 0; t < 4; ++t) {
        int gn = tn4 * 64 + t * 16 + r;
        float bv = bias[gn];
#pragma unroll
        for (int mt = 0; mt < 2; ++mt)
#pragma unroll
            for (int i = 0; i < 4; ++i) {
                int gm = tm * 32 + mt * 16 + quad * 4 + i;
                outB[(size_t)gm * Nc + gn] = (__bf16)(acc[mt][t][i] + bv);
            }
    }
}

// ---- attn (4x4 per n,h) + out-proj GEMM + alpha-blend, fused -------------
__global__ __launch_bounds__(256) void attg3_kernel(
    const __bf16* __restrict__ qkv, const __bf16* __restrict__ outWb,
    const float* __restrict__ outBias, const float* __restrict__ H,
    const float* __restrict__ alphas,
    float* __restrict__ alignedF, __bf16* __restrict__ alignedB)
{
    __shared__ __bf16 obuf[16][280];
    int n0 = blockIdx.x * 4;
    int tid = threadIdx.x;
    int h = tid >> 6, d = tid & 63;
#pragma unroll
    for (int ni = 0; ni < 4; ++ni) {
        int n = n0 + ni;
        float q[4], k[4], vv[4];
#pragma unroll
        for (int s = 0; s < 4; ++s) {
            size_t base = (size_t)(s * kN + n) * 768 + h * 64 + d;
            q[s]  = (float)qkv[base];
            k[s]  = (float)qkv[base + 256];
            vv[s] = (float)qkv[base + 512];
        }
        float att[4][4];
#pragma unroll
        for (int s = 0; s < 4; ++s)
#pragma unroll
            for (int t = 0; t < 4; ++t) {
                float p = q[s] * k[t];
#pragma unroll
                for (int off = 32; off > 0; off >>= 1) p += __shfl_xor(p, off);
                att[s][t] = p * 0.125f;
            }
#pragma unroll
        for (int s = 0; s < 4; ++s) {
            float mx = fmaxf(fmaxf(att[s][0], att[s][1]), fmaxf(att[s][2], att[s][3]));
            float e0 = __expf(att[s][0] - mx), e1 = __expf(att[s][1] - mx);
            float e2 = __expf(att[s][2] - mx), e3 = __expf(att[s][3] - mx);
            float inv = 1.f / (e0 + e1 + e2 + e3);
            float ov = (e0 * vv[0] + e1 * vv[1] + e2 * vv[2] + e3 * vv[3]) * inv;
            obuf[s * 4 + ni][h * 64 + d] = (__bf16)ov;
        }
    }
    __syncthreads();
    int w = tid >> 6, lane = tid & 63;
    int r = lane & 15, quad = lane >> 4;
    f32x4 acc[4] = {};
    for (int k0 = 0; k0 < 256; k0 += 32) {
        bf16x8 a = *(const bf16x8*)&obuf[r][quad * 8 + k0];
#pragma unroll
        for (int t = 0; t < 4; ++t) {
            bf16x8 b = *(const bf16x8*)(outWb + (size_t)(w * 64 + t * 16 + r) * 256 + quad * 8 + k0);
            acc[t] = __builtin_amdgcn_mfma_f32_16x16x32_bf16(a, b, acc[t], 0, 0, 0);
        }
    }
#pragma unroll
    for (int t = 0; t < 4; ++t) {
        int gn = w * 64 + t * 16 + r;
        float bv = outBias[gn];
#pragma unroll
        for (int i = 0; i < 4; ++i) {
            int rl = quad * 4 + i;
            int s = rl >> 2, ni = rl & 3;
            size_t gr = (size_t)(s * kN + n0 + ni);
            float a_ = alphas[s];
            size_t off = gr * kD + gn;
            float res = a_ * (acc[t][i] + bv) + (1.f - a_) * H[off];
            alignedF[off] = res;
            alignedB[off] = (__bf16)res;
        }
    }
}

// ---- stage-2 Q/K/V projections (per-view W) + fused Vmean ----------------
__global__ __launch_bounds__(256) void gemm_qkv3_kernel(
    const __bf16* __restrict__ A, const __bf16* __restrict__ W,
    __bf16* __restrict__ O0, __bf16* __restrict__ O1, __bf16* __restrict__ O2,
    float* __restrict__ Vmean)
{
    int proj = blockIdx.y;
    __bf16* Ob = (proj == 0) ? O0 : (proj == 1) ? O1 : O2;
    const __bf16* Wb = W + (size_t)proj * 4 * 65536;
    int b = blockIdx.x;
    int view = b / 48;
    int tn4 = threadIdx.x >> 6;
    int lane = threadIdx.x & 63;
    int r = lane & 15, quad = lane >> 4;
    const __bf16* Ap = A + (size_t)(b * 32 + r) * kD + quad * 8;
    const __bf16* Bp = Wb + (size_t)view * 65536 + (size_t)(tn4 * 64 + r) * kD + quad * 8;
    f32x4 acc[2][4] = {};
    for (int k0 = 0; k0 < kD; k0 += 32) {
        bf16x8 a0 = *(const bf16x8*)(Ap + k0);
        bf16x8 a1 = *(const bf16x8*)(Ap + (size_t)16 * kD + k0);
#pragma unroll
        for (int t = 0; t < 4; ++t) {
            bf16x8 bb = *(const bf16x8*)(Bp + (size_t)t * 16 * kD + k0);
            acc[0][t] = __builtin_amdgcn_mfma_f32_16x16x32_bf16(a0, bb, acc[0][t], 0, 0, 0);
            acc[1][t] = __builtin_amdgcn_mfma_f32_16x16x32_bf16(a1, bb, acc[1][t], 0, 0, 0);
        }
    }
#pragma unroll
    for (int t = 0; t < 4; ++t) {
        int gn = tn4 * 64 + t * 16 + r;
#pragma unroll
        for (int mt = 0; mt < 2; ++mt)
#pragma unroll
            for (int i = 0; i < 4; ++i) {
                int gm = b * 32 + mt * 16 + quad * 4 + i;
                Ob[(size_t)gm * kD + gn] = (__bf16)acc[mt][t][i];
            }
    }
    if (proj == 2) {
#pragma unroll
        for (int t = 0; t < 4; ++t) {
            float cs = 0.f;
#pragma unroll
            for (int mt = 0; mt < 2; ++mt)
#pragma unroll
                for (int i = 0; i < 4; ++i) cs += acc[mt][t][i];
            cs += __shfl_xor(cs, 16);
            cs += __shfl_xor(cs, 32);
            if (quad == 0)
                atomicAdd(&Vmean[view * kD + tn4 * 64 + t * 16 + r], cs * (1.f / 1536.f));
        }
    }
}

// ---- crcva: topk (wave-per-row) + scores + softmax + gather + fuse -------
// XCD swizzle: p fixed per XCD (blockIdx%8) to keep Kn/Vn/Qn slices L2-hot.
__global__ __launch_bounds__(256) void crcva_kernel(
    const float* __restrict__ C,
    const __bf16* __restrict__ Qn, const __bf16* __restrict__ Kn,
    const __bf16* __restrict__ Vn, const float* __restrict__ Vmean,
    const float* __restrict__ alignedF, const float* __restrict__ H,
    const float* __restrict__ alpha_align, const float* __restrict__ beta,
    float* __restrict__ out)
{
    int gid = blockIdx.x;
    int j8  = gid & 7;
    int p   = j8 & 3;
    int n   = ((gid >> 3) << 1) | (j8 >> 2);
    int tid = threadIdx.x;
    int w = tid >> 6, lane = tid & 63;
    __shared__ unsigned int hist[3][257];
    __shared__ unsigned int sbin[3];
    __shared__ unsigned int idxl[3][kTopK];
    __shared__ unsigned int scnt[3];
    __shared__ float qsh[kD];
    __shared__ float wsh[96];
    __shared__ int   osh[96];
    __shared__ float part[4][kD];

    if (w < 3) {
        // ---- wave-local exact top-32 radix select on row (p, q, n) ----
        int q = w + (w >= p ? 1 : 0);
        const float* row = C + ((size_t)((p * kV + q) * kN + n)) * kN;
        unsigned int key[24];
#pragma unroll
        for (int j = 0; j < 6; ++j) {
            f32x4 v4 = __builtin_nontemporal_load((const f32x4*)(row + j * 256 + lane * 4));
#pragma unroll
            for (int e = 0; e < 4; ++e) {
                unsigned int u = __float_as_uint(v4[e]);
                key[j * 4 + e] = (u & 0x80000000u) ? ~u : (u | 0x80000000u);
            }
        }
        if (lane == 0) scnt[w] = 0;
        unsigned int pref = 0, need = kTopK;
#pragma unroll
        for (int pass = 0; pass < 4; ++pass) {
            const int shift = 24 - 8 * pass;
#pragma unroll
            for (int k2 = 0; k2 < 4; ++k2) hist[w][lane * 4 + k2] = 0;
            if (lane == 0) sbin[w] = 0;
            __builtin_amdgcn_wave_barrier();
#pragma unroll
            for (int j = 0; j < 24; ++j) {
                unsigned int k = key[j];
                bool match = (pass == 0) ? (k > 0x80000000u)            // positives only
                                         : (((k ^ pref) >> (shift + 8)) == 0);
                if (match) atomicAdd(&hist[w][(k >> shift) & 255u], 1u);
            }
            __builtin_amdgcn_wave_barrier();
            unsigned int h0 = hist[w][lane*4+0], h1 = hist[w][lane*4+1];
            unsigned int h2 = hist[w][lane*4+2], h3 = hist[w][lane*4+3];
            unsigned int s3 = h3, s2 = h2 + s3, s1 = h1 + s2, s0 = h0 + s1;
            unsigned int run = s0;
#pragma unroll
            for (int off = 1; off < 64; off <<= 1) {
                unsigned int v = __shfl_down(run, off);
                if (lane + off < 64) run += v;
            }
            if (pass == 0) {
                unsigned int tot = __shfl(run, 0);   // total positive count
                need = need < tot ? need : tot;
            }
            unsigned int above = run - s0;
            unsigned int suf[4]  = {above+s0, above+s1, above+s2, above+s3};
            unsigned int sufN[4] = {above+s1, above+s2, above+s3, above};
#pragma unroll
            for (int k2 = 0; k2 < 4; ++k2)
                if (suf[k2] >= need && sufN[k2] < need)
                    sbin[w] = ((unsigned int)(lane*4 + k2) << 16) | sufN[k2];
            __builtin_amdgcn_wave_barrier();
            unsigned int pk = sbin[w];
            pref |= (pk >> 16) << shift;
            need -= (pk & 0xffffu);
            __builtin_amdgcn_wave_barrier();
        }
        unsigned int T = pref;
        // equals count (wave-wide)
        unsigned int eq = 0;
#pragma unroll
        for (int j = 0; j < 24; ++j) eq += (key[j] == T) ? 1u : 0u;
#pragma unroll
        for (int off = 1; off < 64; off <<= 1) eq += __shfl_xor(eq, off);
        if (eq == need) {
            // fast path (no cross-boundary ties): set = {k >= T, positive}
#pragma unroll
            for (int j = 0; j < 24; ++j) {
                unsigned int k = key[j];
                if (k >= T && k > 0x80000000u) {
                    unsigned int pos = atomicAdd(&scnt[w], 1u);
                    idxl[w][pos] = (unsigned int)((j >> 2) * 256 + lane * 4 + (j & 3));
                }
            }
        } else {
            // rare: jax tie rule — equals taken in ascending index order
            unsigned int eqBefore = 0;
            unsigned long long below = (1ull << lane) - 1ull;
            for (int j4 = 0; j4 < 6; ++j4) {
                unsigned long long m[4];
#pragma unroll
                for (int e = 0; e < 4; ++e) m[e] = __ballot(key[j4 * 4 + e] == T);
#pragma unroll
                for (int e = 0; e < 4; ++e) {
                    unsigned int k = key[j4 * 4 + e];
                    unsigned int rank = eqBefore;
#pragma unroll
                    for (int e2 = 0; e2 < 4; ++e2) rank += (unsigned int)__popcll(m[e2] & below);
                    for (int e2 = 0; e2 < e; ++e2) rank += (unsigned int)((m[e2] >> lane) & 1ull);
                    bool iseq = (k == T);
                    bool take = (k > T) || (iseq && rank < need);
                    if (take && k > 0x80000000u) {
                        unsigned int pos = atomicAdd(&scnt[w], 1u);
                        idxl[w][pos] = (unsigned int)(j4 * 256 + lane * 4 + e);
                    }
                }
                eqBefore += (unsigned int)(__popcll(m[0]) + __popcll(m[1])
                                         + __popcll(m[2]) + __popcll(m[3]));
            }
        }
    } else {
        // wave 3: stage Qn row into LDS as f32
        bf16x4 qv = *(const bf16x4*)(Qn + ((size_t)p * kN + n) * kD + lane * 4);
#pragma unroll
        for (int e = 0; e < 4; ++e) qsh[lane * 4 + e] = (float)qv[e];
    }
    __syncthreads();

    // ---- scores + per-(p,q) softmax (2 threads per candidate row) ----
    if (tid < 192) {
        int j = tid >> 1, half = tid & 1;
        int g = j >> 5, r = j & 31;
        int q = g + (g >= p ? 1 : 0);
        int cnt = (int)scnt[g];
        bool valid = (r < cnt);
        int m = valid ? (int)idxl[g][r] : 0;
        int off = valid ? (q * kN + m) * kD : 0;
        float s = 0.f;
        if (valid) {
            const __bf16* kr = Kn + off + half * 128;
            const float*  qh = qsh + half * 128;
            float a0 = 0.f, a1 = 0.f, a2 = 0.f, a3 = 0.f;
#pragma unroll
            for (int dd = 0; dd < 128; dd += 32) {
                bf16x8 k0 = *(const bf16x8*)(kr + dd);
                bf16x8 k1 = *(const bf16x8*)(kr + dd + 8);
                bf16x8 k2 = *(const bf16x8*)(kr + dd + 16);
                bf16x8 k3 = *(const bf16x8*)(kr + dd + 24);
                const float* q0 = qh + dd;
#pragma unroll
                for (int e = 0; e < 8; ++e) {
                    a0 += q0[e]      * (float)k0[e];
                    a1 += q0[e + 8]  * (float)k1[e];
                    a2 += q0[e + 16] * (float)k2[e];
                    a3 += q0[e + 24] * (float)k3[e];
                }
            }
            s = (a0 + a1) + (a2 + a3);
        }
        s += __shfl_xor(s, 1);
        float sc = valid ? s * 0.0625f : -1e30f;
        float mx = sc;
#pragma unroll
        for (int o2 = 2; o2 <= 32; o2 <<= 1) mx = fmaxf(mx, __shfl_xor(mx, o2));
        float e = valid ? __expf(sc - mx) : 0.f;
        float ss = e;
#pragma unroll
        for (int o2 = 2; o2 <= 32; o2 <<= 1) ss += __shfl_xor(ss, o2);
        if (half == 0) {
            wsh[j] = (ss > 0.f) ? e / ss : 0.f;
            osh[j] = off;
        }
    }
    __syncthreads();

    // ---- weighted V gather: wave w covers 24 rows, 2 rows per iter ----
    {
        int half32 = lane >> 5, l32 = lane & 31;
        float a[8] = {};
#pragma unroll
        for (int it = 0; it < 12; ++it) {
            int j = w * 24 + it * 2 + half32;
            float wt = wsh[j];
            bf16x8 v = *(const bf16x8*)(Vn + osh[j] + l32 * 8);
#pragma unroll
            for (int e = 0; e < 8; ++e) a[e] += wt * (float)v[e];
        }
#pragma unroll
        for (int e = 0; e < 8; ++e) a[e] += __shfl_xor(a[e], 32);
        if (half32 == 0) {
#pragma unroll
            for (int e = 0; e < 8; ++e) part[w][l32 * 8 + e] = a[e];
        }
    }
    __syncthreads();

    float acc = Vmean[p * kD + tid]
              + part[0][tid] + part[1][tid] + part[2][tid] + part[3][tid];
    float aa = 1.f / (1.f + __expf(-alpha_align[0]));
    float bt = beta[0];
    size_t off = ((size_t)p * kN + n) * kD + tid;
    float al = alignedF[off];
    float f  = fmaxf(aa * al + (1.f - aa) * acc, 0.f);
    out[off] = H[off] * bt + (1.f - bt) * f;
}

extern "C" void kernel_launch(void* const* d_in, const int* in_sizes, int n_in,
                              void* d_out, int out_size, void* d_ws, size_t ws_size,
                              hipStream_t stream)
{
    const float* H        = (const float*)d_in[0];
    const float* C        = (const float*)d_in[1];
    const float* WQ       = (const float*)d_in[2];
    const float* WK       = (const float*)d_in[3];
    const float* WV       = (const float*)d_in[4];
    const float* inW      = (const float*)d_in[5];
    const float* inB      = (const float*)d_in[6];
    const float* outW     = (const float*)d_in[7];
    const float* outBias  = (const float*)d_in[8];
    const float* alphas   = (const float*)d_in[9];
    const float* alpha_al = (const float*)d_in[10];
    const float* beta     = (const float*)d_in[11];
    float* out = (float*)d_out;

    char* w = (char*)d_ws;
    __bf16* Hb       = (__bf16*)w;  w += (size_t)6144 * 256 * 2;
    __bf16* inWb     = (__bf16*)w;  w += (size_t)768 * 256 * 2;
    __bf16* outWb    = (__bf16*)w;  w += (size_t)256 * 256 * 2;
    __bf16* Wqkvb    = (__bf16*)w;  w += (size_t)3 * 4 * 256 * 256 * 2;
    __bf16* qkv      = (__bf16*)w;  w += (size_t)6144 * 768 * 2;
    __bf16* alignedB = (__bf16*)w;  w += (size_t)6144 * 256 * 2;
    float*  alignedF = (float*)w;   w += (size_t)6144 * 256 * 4;
    __bf16* Qn       = (__bf16*)w;  w += (size_t)6144 * 256 * 2;
    __bf16* Kn       = (__bf16*)w;  w += (size_t)6144 * 256 * 2;
    __bf16* Vn       = (__bf16*)w;  w += (size_t)6144 * 256 * 2;
    float*  Vmean    = (float*)w;   w += (size_t)4 * 256 * 4;

    // 1) pre-convert + zero Vmean
    convert_kernel<<<2560, 256, 0, stream>>>(H, inW, outW, WQ, WK, WV,
                                             Hb, inWb, outWb, Wqkvb, Vmean);
    // 2) qkv = Hb @ inWb^T + inB
    gemm_qkv_kernel<<<576, 256, 0, stream>>>(Hb, inWb, inB, qkv);
    // 3) attn + out-proj + alpha-blend (o stays in LDS)
    attg3_kernel<<<384, 256, 0, stream>>>(qkv, outWb, outBias, H, alphas,
                                          alignedF, alignedB);
    // 4) Q/K/V projections (per-view W) + fused Vmean
    gemm_qkv3_kernel<<<dim3(192, 3), 256, 0, stream>>>(alignedB, Wqkvb,
                                                       Qn, Kn, Vn, Vmean);
    // 5) topk + scores + softmax + gather + final fuse (XCD-swizzled)
    crcva_kernel<<<6144, 256, 0, stream>>>(C, Qn, Kn, Vn, Vmean,
        alignedF, H, alpha_al, beta, out);
}

// Round 8
// 363.003 us; speedup vs baseline: 2.8878x; 1.0162x over previous
//
#include <hip/hip_runtime.h>
#include <hip/hip_bf16.h>
#include <math.h>

typedef __bf16 bf16x8 __attribute__((ext_vector_type(8)));
typedef __bf16 bf16x4 __attribute__((ext_vector_type(4)));
typedef float  f32x4  __attribute__((ext_vector_type(4)));

static constexpr int kV = 4;
static constexpr int kN = 1536;
static constexpr int kD = 256;
static constexpr int kTopK = 32;

// ---- f32 -> bf16 pre-convert of H + all weights; also zeros Vmean --------
__global__ __launch_bounds__(256) void convert_kernel(
    const float* __restrict__ H, const float* __restrict__ inW,
    const float* __restrict__ outW, const float* __restrict__ WQ,
    const float* __restrict__ WK, const float* __restrict__ WV,
    __bf16* __restrict__ Hb, __bf16* __restrict__ inWb,
    __bf16* __restrict__ outWb, __bf16* __restrict__ Wqkvb,
    float* __restrict__ Vmean)
{
    if (blockIdx.x == 0) {
        f32x4 z = {0.f, 0.f, 0.f, 0.f};
        *(f32x4*)(Vmean + threadIdx.x * 4) = z;   // 256*4 = 1024 floats
    }
    int idx = (blockIdx.x * 256 + threadIdx.x) * 4;
    const float* src; __bf16* dst; int off;
    if      (idx < 1572864) { src = H;    dst = Hb;             off = idx; }
    else if (idx < 1769472) { src = inW;  dst = inWb;           off = idx - 1572864; }
    else if (idx < 1835008) { src = outW; dst = outWb;          off = idx - 1769472; }
    else if (idx < 2097152) { src = WQ;   dst = Wqkvb;          off = idx - 1835008; }
    else if (idx < 2359296) { src = WK;   dst = Wqkvb + 262144; off = idx - 2097152; }
    else                    { src = WV;   dst = Wqkvb + 524288; off = idx - 2359296; }
    f32x4 v = *(const f32x4*)(src + off);
    bf16x4 b;
#pragma unroll
    for (int j = 0; j < 4; ++j) b[j] = (__bf16)v[j];
    *(bf16x4*)(dst + off) = b;
}

// ---- qkv = Hb @ inWb^T + inB; wave tile 32x64 ----------------------------
__global__ __launch_bounds__(256) void gemm_qkv_kernel(
    const __bf16* __restrict__ A, const __bf16* __restrict__ Bm,
    const float* __restrict__ bias, __bf16* __restrict__ outB)
{
    const int Nc = 768, K = 256;
    int wave = blockIdx.x * 4 + (threadIdx.x >> 6);
    int tm  = wave / 12;
    int tn4 = wave - tm * 12;
    int lane = threadIdx.x & 63;
    int r    = lane & 15;
    int quad = lane >> 4;
    const __bf16* Ap = A + (size_t)(tm * 32 + r) * K + quad * 8;
    const __bf16* Bp = Bm + (size_t)(tn4 * 64 + r) * K + quad * 8;
    f32x4 acc[2][4] = {};
    for (int k0 = 0; k0 < K; k0 += 32) {
        bf16x8 a0 = *(const bf16x8*)(Ap + k0);
        bf16x8 a1 = *(const bf16x8*)(Ap + (size_t)16 * K + k0);
#pragma unroll
        for (int t = 0; t < 4; ++t) {
            bf16x8 b = *(const bf16x8*)(Bp + (size_t)t * 16 * K + k0);
            acc[0][t] = __builtin_amdgcn_mfma_f32_16x16x32_bf16(a0, b, acc[0][t], 0, 0, 0);
            acc[1][t] = __builtin_amdgcn_mfma_f32_16x16x32_bf16(a1, b, acc[1][t], 0, 0, 0);
        }
    }
#pragma unroll
    for (int t = 0; t < 4; ++t) {
        int gn = tn4 * 64 + t * 16 + r;
        float bv = bias[gn];
#pragma unroll
        for (int mt = 0; mt < 2; ++mt)
#pragma unroll
            for (int i = 0; i < 4; ++i) {
                int gm = tm * 32 + mt * 16 + quad * 4 + i;
                outB[(size_t)gm * Nc + gn] = (__bf16)(acc[mt][t][i] + bv);
            }
    }
}

// ---- attn (4x4 per n,h) + out-proj GEMM + alpha-blend, fused -------------
__global__ __launch_bounds__(256) void attg3_kernel(
    const __bf16* __restrict__ qkv, const __bf16* __restrict__ outWb,
    const float* __restrict__ outBias, const float* __restrict__ H,
    const float* __restrict__ alphas,
    float* __restrict__ alignedF, __bf16* __restrict__ alignedB)
{
    __shared__ __bf16 obuf[16][280];
    int n0 = blockIdx.x * 4;
    int tid = threadIdx.x;
    int h = tid >> 6, d = tid & 63;
#pragma unroll
    for (int ni = 0; ni < 4; ++ni) {
        int n = n0 + ni;
        float q[4], k[4], vv[4];
#pragma unroll
        for (int s = 0; s < 4; ++s) {
            size_t base = (size_t)(s * kN + n) * 768 + h * 64 + d;
            q[s]  = (float)qkv[base];
            k[s]  = (float)qkv[base + 256];
            vv[s] = (float)qkv[base + 512];
        }
        float att[4][4];
#pragma unroll
        for (int s = 0; s < 4; ++s)
#pragma unroll
            for (int t = 0; t < 4; ++t) {
                float p = q[s] * k[t];
#pragma unroll
                for (int off = 32; off > 0; off >>= 1) p += __shfl_xor(p, off);
                att[s][t] = p * 0.125f;
            }
#pragma unroll
        for (int s = 0; s < 4; ++s) {
            float mx = fmaxf(fmaxf(att[s][0], att[s][1]), fmaxf(att[s][2], att[s][3]));
            float e0 = __expf(att[s][0] - mx), e1 = __expf(att[s][1] - mx);
            float e2 = __expf(att[s][2] - mx), e3 = __expf(att[s][3] - mx);
            float inv = 1.f / (e0 + e1 + e2 + e3);
            float ov = (e0 * vv[0] + e1 * vv[1] + e2 * vv[2] + e3 * vv[3]) * inv;
            obuf[s * 4 + ni][h * 64 + d] = (__bf16)ov;
        }
    }
    __syncthreads();
    int w = tid >> 6, lane = tid & 63;
    int r = lane & 15, quad = lane >> 4;
    f32x4 acc[4] = {};
    for (int k0 = 0; k0 < 256; k0 += 32) {
        bf16x8 a = *(const bf16x8*)&obuf[r][quad * 8 + k0];
#pragma unroll
        for (int t = 0; t < 4; ++t) {
            bf16x8 b = *(const bf16x8*)(outWb + (size_t)(w * 64 + t * 16 + r) * 256 + quad * 8 + k0);
            acc[t] = __builtin_amdgcn_mfma_f32_16x16x32_bf16(a, b, acc[t], 0, 0, 0);
        }
    }
#pragma unroll
    for (int t = 0; t < 4; ++t) {
        int gn = w * 64 + t * 16 + r;
        float bv = outBias[gn];
#pragma unroll
        for (int i = 0; i < 4; ++i) {
            int rl = quad * 4 + i;
            int s = rl >> 2, ni = rl & 3;
            size_t gr = (size_t)(s * kN + n0 + ni);
            float a_ = alphas[s];
            size_t off = gr * kD + gn;
            float res = a_ * (acc[t][i] + bv) + (1.f - a_) * H[off];
            alignedF[off] = res;
            alignedB[off] = (__bf16)res;
        }
    }
}

// ---- stage-2 Q/K/V projections (per-view W) + fused Vmean ----------------
__global__ __launch_bounds__(256) void gemm_qkv3_kernel(
    const __bf16* __restrict__ A, const __bf16* __restrict__ W,
    __bf16* __restrict__ O0, __bf16* __restrict__ O1, __bf16* __restrict__ O2,
    float* __restrict__ Vmean)
{
    int proj = blockIdx.y;
    __bf16* Ob = (proj == 0) ? O0 : (proj == 1) ? O1 : O2;
    const __bf16* Wb = W + (size_t)proj * 4 * 65536;
    int b = blockIdx.x;
    int view = b / 48;
    int tn4 = threadIdx.x >> 6;
    int lane = threadIdx.x & 63;
    int r = lane & 15, quad = lane >> 4;
    const __bf16* Ap = A + (size_t)(b * 32 + r) * kD + quad * 8;
    const __bf16* Bp = Wb + (size_t)view * 65536 + (size_t)(tn4 * 64 + r) * kD + quad * 8;
    f32x4 acc[2][4] = {};
    for (int k0 = 0; k0 < kD; k0 += 32) {
        bf16x8 a0 = *(const bf16x8*)(Ap + k0);
        bf16x8 a1 = *(const bf16x8*)(Ap + (size_t)16 * kD + k0);
#pragma unroll
        for (int t = 0; t < 4; ++t) {
            bf16x8 bb = *(const bf16x8*)(Bp + (size_t)t * 16 * kD + k0);
            acc[0][t] = __builtin_amdgcn_mfma_f32_16x16x32_bf16(a0, bb, acc[0][t], 0, 0, 0);
            acc[1][t] = __builtin_amdgcn_mfma_f32_16x16x32_bf16(a1, bb, acc[1][t], 0, 0, 0);
        }
    }
#pragma unroll
    for (int t = 0; t < 4; ++t) {
        int gn = tn4 * 64 + t * 16 + r;
#pragma unroll
        for (int mt = 0; mt < 2; ++mt)
#pragma unroll
            for (int i = 0; i < 4; ++i) {
                int gm = b * 32 + mt * 16 + quad * 4 + i;
                Ob[(size_t)gm * kD + gn] = (__bf16)acc[mt][t][i];
            }
    }
    if (proj == 2) {
#pragma unroll
        for (int t = 0; t < 4; ++t) {
            float cs = 0.f;
#pragma unroll
            for (int mt = 0; mt < 2; ++mt)
#pragma unroll
                for (int i = 0; i < 4; ++i) cs += acc[mt][t][i];
            cs += __shfl_xor(cs, 16);
            cs += __shfl_xor(cs, 32);
            if (quad == 0)
                atomicAdd(&Vmean[view * kD + tn4 * 64 + t * 16 + r], cs * (1.f / 1536.f));
        }
    }
}

// ---- crcva: topk (wave-per-row, prefiltered) + scores + gather + fuse ----
__global__ __launch_bounds__(256) void crcva_kernel(
    const float* __restrict__ C,
    const __bf16* __restrict__ Qn, const __bf16* __restrict__ Kn,
    const __bf16* __restrict__ Vn, const float* __restrict__ Vmean,
    const float* __restrict__ alignedF, const float* __restrict__ H,
    const float* __restrict__ alpha_align, const float* __restrict__ beta,
    float* __restrict__ out)
{
    int gid = blockIdx.x;
    int j8  = gid & 7;
    int p   = j8 & 3;
    int n   = ((gid >> 3) << 1) | (j8 >> 2);
    int tid = threadIdx.x;
    int w = tid >> 6, lane = tid & 63;
    __shared__ unsigned int hist[3][257];
    __shared__ unsigned int sbin[3];
    __shared__ unsigned int idxl[3][kTopK];
    __shared__ unsigned int scnt[3];
    __shared__ float qsh[kD];
    __shared__ float wsh[96];
    __shared__ int   osh[96];
    __shared__ float part[4][kD];

    // prefetch epilogue operands (latency hidden behind topk phase)
    size_t eoff = ((size_t)p * kN + n) * kD + tid;
    float pre_al = alignedF[eoff];
    float pre_h  = H[eoff];
    float pre_vm = Vmean[p * kD + tid];
    float pre_aa = alpha_align[0];
    float pre_bt = beta[0];

    if (w < 3) {
        // ---- wave-local exact top-32 radix select on row (p, q, n) ----
        int q = w + (w >= p ? 1 : 0);
        const float* row = C + ((size_t)((p * kV + q) * kN + n)) * kN;
        unsigned int key[24];
#pragma unroll
        for (int j = 0; j < 6; ++j) {
            f32x4 v4 = __builtin_nontemporal_load((const f32x4*)(row + j * 256 + lane * 4));
#pragma unroll
            for (int e = 0; e < 4; ++e) {
                unsigned int u = __float_as_uint(v4[e]);
                key[j * 4 + e] = (u & 0x80000000u) ? ~u : (u | 0x80000000u);
            }
        }
        if (lane == 0) scnt[w] = 0;
        // candidate prefilter: value > 1.6  (key > transform(1.6f) = 0xBFCCCCCD)
        const unsigned int T0 = 0xBFCCCCCDu;
        unsigned int cand = 0;
#pragma unroll
        for (int j = 0; j < 24; ++j) cand |= (key[j] > T0) ? (1u << j) : 0u;
        unsigned int myc = (unsigned int)__popc(cand);
#pragma unroll
        for (int off = 1; off < 64; off <<= 1) myc += __shfl_xor(myc, off);
        if (myc < kTopK) {
            // fallback (data-independent correctness): all positives
            cand = 0;
#pragma unroll
            for (int j = 0; j < 24; ++j) cand |= (key[j] > 0x80000000u) ? (1u << j) : 0u;
        }
        unsigned int pref = 0, need = kTopK;
#pragma unroll
        for (int pass = 0; pass < 4; ++pass) {
            const int shift = 24 - 8 * pass;
#pragma unroll
            for (int k2 = 0; k2 < 4; ++k2) hist[w][lane * 4 + k2] = 0;
            if (lane == 0) sbin[w] = 0;
            __builtin_amdgcn_wave_barrier();
#pragma unroll
            for (int j = 0; j < 24; ++j) {
                unsigned int k = key[j];
                bool match = ((cand >> j) & 1u) &&
                             ((pass == 0) || (((k ^ pref) >> (shift + 8)) == 0));
                if (match) atomicAdd(&hist[w][(k >> shift) & 255u], 1u);
            }
            __builtin_amdgcn_wave_barrier();
            unsigned int h0 = hist[w][lane*4+0], h1 = hist[w][lane*4+1];
            unsigned int h2 = hist[w][lane*4+2], h3 = hist[w][lane*4+3];
            unsigned int s3 = h3, s2 = h2 + s3, s1 = h1 + s2, s0 = h0 + s1;
            unsigned int run = s0;
#pragma unroll
            for (int off = 1; off < 64; off <<= 1) {
                unsigned int v = __shfl_down(run, off);
                if (lane + off < 64) run += v;
            }
            if (pass == 0) {
                unsigned int tot = __shfl(run, 0);   // total candidate count
                need = need < tot ? need : tot;
            }
            unsigned int above = run - s0;
            unsigned int suf[4]  = {above+s0, above+s1, above+s2, above+s3};
            unsigned int sufN[4] = {above+s1, above+s2, above+s3, above};
#pragma unroll
            for (int k2 = 0; k2 < 4; ++k2)
                if (suf[k2] >= need && sufN[k2] < need)
                    sbin[w] = ((unsigned int)(lane*4 + k2) << 16) | sufN[k2];
            __builtin_amdgcn_wave_barrier();
            unsigned int pk = sbin[w];
            pref |= (pk >> 16) << shift;
            need -= (pk & 0xffffu);
            __builtin_amdgcn_wave_barrier();
        }
        unsigned int T = pref;
        // equals count (wave-wide), candidates only
        unsigned int eq = 0;
#pragma unroll
        for (int j = 0; j < 24; ++j)
            eq += (((cand >> j) & 1u) && key[j] == T) ? 1u : 0u;
#pragma unroll
        for (int off = 1; off < 64; off <<= 1) eq += __shfl_xor(eq, off);
        if (eq == need) {
            // fast path (no cross-boundary ties): set = {candidate, k >= T}
#pragma unroll
            for (int j = 0; j < 24; ++j) {
                if (((cand >> j) & 1u) && key[j] >= T) {
                    unsigned int pos = atomicAdd(&scnt[w], 1u);
                    idxl[w][pos] = (unsigned int)((j >> 2) * 256 + lane * 4 + (j & 3));
                }
            }
        } else {
            // rare: jax tie rule — equals taken in ascending index order
            unsigned int eqBefore = 0;
            unsigned long long below = (1ull << lane) - 1ull;
            for (int j4 = 0; j4 < 6; ++j4) {
                unsigned long long m[4];
#pragma unroll
                for (int e = 0; e < 4; ++e)
                    m[e] = __ballot(((cand >> (j4*4+e)) & 1u) && key[j4 * 4 + e] == T);
#pragma unroll
                for (int e = 0; e < 4; ++e) {
                    unsigned int k = key[j4 * 4 + e];
                    bool inc = (cand >> (j4*4+e)) & 1u;
                    unsigned int rank = eqBefore;
#pragma unroll
                    for (int e2 = 0; e2 < 4; ++e2) rank += (unsigned int)__popcll(m[e2] & below);
                    for (int e2 = 0; e2 < e; ++e2) rank += (unsigned int)((m[e2] >> lane) & 1ull);
                    bool iseq = inc && (k == T);
                    bool take = (inc && k > T) || (iseq && rank < need);
                    if (take) {
                        unsigned int pos = atomicAdd(&scnt[w], 1u);
                        idxl[w][pos] = (unsigned int)(j4 * 256 + lane * 4 + e);
                    }
                }
                eqBefore += (unsigned int)(__popcll(m[0]) + __popcll(m[1])
                                         + __popcll(m[2]) + __popcll(m[3]));
            }
        }
    } else {
        // wave 3: stage Qn row into LDS as f32
        bf16x4 qv = *(const bf16x4*)(Qn + ((size_t)p * kN + n) * kD + lane * 4);
#pragma unroll
        for (int e = 0; e < 4; ++e) qsh[lane * 4 + e] = (float)qv[e];
    }
    __syncthreads();

    // ---- scores + per-(p,q) softmax (2 threads per candidate row) ----
    if (tid < 192) {
        int j = tid >> 1, half = tid & 1;
        int g = j >> 5, r = j & 31;
        int q = g + (g >= p ? 1 : 0);
        int cnt = (int)scnt[g];
        bool valid = (r < cnt);
        int m = valid ? (int)idxl[g][r] : 0;
        int off = valid ? (q * kN + m) * kD : 0;
        float s = 0.f;
        if (valid) {
            const __bf16* kr = Kn + off + half * 128;
            const float*  qh = qsh + half * 128;
            float a0 = 0.f, a1 = 0.f, a2 = 0.f, a3 = 0.f;
#pragma unroll
            for (int dd = 0; dd < 128; dd += 32) {
                bf16x8 k0 = *(const bf16x8*)(kr + dd);
                bf16x8 k1 = *(const bf16x8*)(kr + dd + 8);
                bf16x8 k2 = *(const bf16x8*)(kr + dd + 16);
                bf16x8 k3 = *(const bf16x8*)(kr + dd + 24);
                const float* q0 = qh + dd;
#pragma unroll
                for (int e = 0; e < 8; ++e) {
                    a0 += q0[e]      * (float)k0[e];
                    a1 += q0[e + 8]  * (float)k1[e];
                    a2 += q0[e + 16] * (float)k2[e];
                    a3 += q0[e + 24] * (float)k3[e];
                }
            }
            s = (a0 + a1) + (a2 + a3);
        }
        s += __shfl_xor(s, 1);
        float sc = valid ? s * 0.0625f : -1e30f;
        float mx = sc;
#pragma unroll
        for (int o2 = 2; o2 <= 32; o2 <<= 1) mx = fmaxf(mx, __shfl_xor(mx, o2));
        float e = valid ? __expf(sc - mx) : 0.f;
        float ss = e;
#pragma unroll
        for (int o2 = 2; o2 <= 32; o2 <<= 1) ss += __shfl_xor(ss, o2);
        if (half == 0) {
            wsh[j] = (ss > 0.f) ? e / ss : 0.f;
            osh[j] = off;
        }
    }
    __syncthreads();

    // ---- weighted V gather: wave w covers 24 rows, 2 rows per iter ----
    {
        int half32 = lane >> 5, l32 = lane & 31;
        float a[8] = {};
#pragma unroll
        for (int it = 0; it < 12; ++it) {
            int j = w * 24 + it * 2 + half32;
            float wt = wsh[j];
            bf16x8 v = *(const bf16x8*)(Vn + osh[j] + l32 * 8);
#pragma unroll
            for (int e = 0; e < 8; ++e) a[e] += wt * (float)v[e];
        }
#pragma unroll
        for (int e = 0; e < 8; ++e) a[e] += __shfl_xor(a[e], 32);
        if (half32 == 0) {
#pragma unroll
            for (int e = 0; e < 8; ++e) part[w][l32 * 8 + e] = a[e];
        }
    }
    __syncthreads();

    float acc = pre_vm + part[0][tid] + part[1][tid] + part[2][tid] + part[3][tid];
    float aa = 1.f / (1.f + __expf(-pre_aa));
    float f  = fmaxf(aa * pre_al + (1.f - aa) * acc, 0.f);
    out[eoff] = pre_h * pre_bt + (1.f - pre_bt) * f;
}

extern "C" void kernel_launch(void* const* d_in, const int* in_sizes, int n_in,
                              void* d_out, int out_size, void* d_ws, size_t ws_size,
                              hipStream_t stream)
{
    const float* H        = (const float*)d_in[0];
    const float* C        = (const float*)d_in[1];
    const float* WQ       = (const float*)d_in[2];
    const float* WK       = (const float*)d_in[3];
    const float* WV       = (const float*)d_in[4];
    const float* inW      = (const float*)d_in[5];
    const float* inB      = (const float*)d_in[6];
    const float* outW     = (const float*)d_in[7];
    const float* outBias  = (const float*)d_in[8];
    const float* alphas   = (const float*)d_in[9];
    const float* alpha_al = (const float*)d_in[10];
    const float* beta     = (const float*)d_in[11];
    float* out = (float*)d_out;

    char* w = (char*)d_ws;
    __bf16* Hb       = (__bf16*)w;  w += (size_t)6144 * 256 * 2;
    __bf16* inWb     = (__bf16*)w;  w += (size_t)768 * 256 * 2;
    __bf16* outWb    = (__bf16*)w;  w += (size_t)256 * 256 * 2;
    __bf16* Wqkvb    = (__bf16*)w;  w += (size_t)3 * 4 * 256 * 256 * 2;
    __bf16* qkv      = (__bf16*)w;  w += (size_t)6144 * 768 * 2;
    __bf16* alignedB = (__bf16*)w;  w += (size_t)6144 * 256 * 2;
    float*  alignedF = (float*)w;   w += (size_t)6144 * 256 * 4;
    __bf16* Qn       = (__bf16*)w;  w += (size_t)6144 * 256 * 2;
    __bf16* Kn       = (__bf16*)w;  w += (size_t)6144 * 256 * 2;
    __bf16* Vn       = (__bf16*)w;  w += (size_t)6144 * 256 * 2;
    float*  Vmean    = (float*)w;   w += (size_t)4 * 256 * 4;

    // 1) pre-convert + zero Vmean
    convert_kernel<<<2560, 256, 0, stream>>>(H, inW, outW, WQ, WK, WV,
                                             Hb, inWb, outWb, Wqkvb, Vmean);
    // 2) qkv = Hb @ inWb^T + inB
    gemm_qkv_kernel<<<576, 256, 0, stream>>>(Hb, inWb, inB, qkv);
    // 3) attn + out-proj + alpha-blend (o stays in LDS)
    attg3_kernel<<<384, 256, 0, stream>>>(qkv, outWb, outBias, H, alphas,
                                          alignedF, alignedB);
    // 4) Q/K/V projections (per-view W) + fused Vmean
    gemm_qkv3_kernel<<<dim3(192, 3), 256, 0, stream>>>(alignedB, Wqkvb,
                                                       Qn, Kn, Vn, Vmean);
    // 5) topk + scores + softmax + gather + final fuse (XCD-swizzled)
    crcva_kernel<<<6144, 256, 0, stream>>>(C, Qn, Kn, Vn, Vmean,
        alignedF, H, alpha_al, beta, out);
}